// Round 1
// baseline (1522.720 us; speedup 1.0000x reference)
//
#include <hip/hip_runtime.h>
#include <hip/hip_bf16.h>
#include <math.h>

#define B_   8
#define T_   12
#define NN   325
#define DD   256
#define HH   8
#define HD   32
#define FFD  1024
#define MTOK (B_*T_*NN)     // 31200 tokens
#define ATT_SCALE 0.17677669529663687f   // 1/sqrt(32)
#define LN_EPS 1e-5f

// ---------------------------------------------------------------------------
// Generic tiled fp32 GEMM: C[M,N] = A[M,K] @ W[K,N] + bias[N], optional GELU.
// BM=BN=64, BK=16, 256 threads, 4x4 microtile per thread.
// ---------------------------------------------------------------------------
#define BM 64
#define BN 64
#define BK 16

__global__ __launch_bounds__(256) void gemm_bias_act(
    const float* __restrict__ A, const float* __restrict__ W,
    const float* __restrict__ bias, float* __restrict__ C,
    int Mr, int Nr, int Kr, int act)
{
  __shared__ float As[BK][BM + 4];   // pad 4: write banks 2-way, reads aligned 16B
  __shared__ float Ws[BK][BN + 4];

  const int m0 = blockIdx.x * BM;
  const int n0 = blockIdx.y * BN;
  const int tid = threadIdx.x;
  const int tx = tid & 15;          // micro col group
  const int ty = tid >> 4;          // micro row group

  const int ca = tid & 15;          // A-tile k index
  const int ra = tid >> 4;          // A-tile row base (16 rows/pass)
  const int cw = tid & 63;          // W-tile n index
  const int rw = tid >> 6;          // W-tile k base (4 rows/pass)

  float acc[4][4] = {};

  for (int k0 = 0; k0 < Kr; k0 += BK) {
    #pragma unroll
    for (int i = 0; i < 4; ++i) {
      int row = ra + 16 * i;
      int gm = m0 + row;
      float val = 0.f;
      if (gm < Mr) val = A[(size_t)gm * Kr + (k0 + ca)];
      As[ca][row] = val;
    }
    #pragma unroll
    for (int i = 0; i < 4; ++i) {
      int krow = rw + 4 * i;
      Ws[krow][cw] = W[(size_t)(k0 + krow) * Nr + (n0 + cw)];
    }
    __syncthreads();

    #pragma unroll
    for (int kk = 0; kk < BK; ++kk) {
      float4 a4 = *reinterpret_cast<const float4*>(&As[kk][ty * 4]);
      float4 b4 = *reinterpret_cast<const float4*>(&Ws[kk][tx * 4]);
      float a[4] = {a4.x, a4.y, a4.z, a4.w};
      float b[4] = {b4.x, b4.y, b4.z, b4.w};
      #pragma unroll
      for (int i = 0; i < 4; ++i)
        #pragma unroll
        for (int j = 0; j < 4; ++j)
          acc[i][j] += a[i] * b[j];
    }
    __syncthreads();
  }

  #pragma unroll
  for (int i = 0; i < 4; ++i) {
    int gm = m0 + ty * 4 + i;
    if (gm >= Mr) continue;
    #pragma unroll
    for (int j = 0; j < 4; ++j) {
      int gn = n0 + tx * 4 + j;
      float c = acc[i][j] + bias[gn];
      if (act == 1) c = 0.5f * c * (1.f + erff(c * 0.70710678118654752f));  // exact GELU
      C[(size_t)gm * Nr + gn] = c;
    }
  }
}

// ---------------------------------------------------------------------------
// Spatial attention: one thread per (group g=b*T+t, head h, query l).
// Online softmax over 325 keys with adjacency mask (score=-1e30 when masked,
// which reproduces the reference's uniform-softmax behavior on all-masked rows).
// ---------------------------------------------------------------------------
__global__ __launch_bounds__(384) void spatial_attn(
    const float* __restrict__ q, const float* __restrict__ k,
    const float* __restrict__ v, const int* __restrict__ adj,
    float* __restrict__ out)
{
  const int g = blockIdx.x;    // 0..95
  const int h = blockIdx.y;    // 0..7
  const int l = threadIdx.x;   // query index
  if (l >= NN) return;

  const float* qp = q + ((size_t)(g * NN + l)) * DD + h * HD;
  float qr[HD];
  #pragma unroll
  for (int d = 0; d < HD; ++d) qr[d] = qp[d];

  float o[HD] = {};
  float mrun = -INFINITY, lrun = 0.f;
  const int* maskrow = adj + (size_t)l * NN;

  for (int m = 0; m < NN; ++m) {
    const float* kp = k + ((size_t)(g * NN + m)) * DD + h * HD;
    float s = 0.f;
    #pragma unroll
    for (int d = 0; d < HD; ++d) s += qr[d] * kp[d];
    s *= ATT_SCALE;
    if (maskrow[m] == 0) s = -1e30f;

    float mnew = fmaxf(mrun, s);
    float corr = __expf(mrun - mnew);
    float p = __expf(s - mnew);
    lrun = lrun * corr + p;
    const float* vp = v + ((size_t)(g * NN + m)) * DD + h * HD;
    #pragma unroll
    for (int d = 0; d < HD; ++d) o[d] = o[d] * corr + p * vp[d];
    mrun = mnew;
  }

  float inv = 1.f / lrun;
  float* op = out + ((size_t)(g * NN + l)) * DD + h * HD;
  #pragma unroll
  for (int d = 0; d < HD; ++d) op[d] = o[d] * inv;
}

// ---------------------------------------------------------------------------
// Temporal attention (causal, T=12): one thread per (b, n, h, t).
// Grouping is (b, n) over t; handled purely by indexing (no transpose).
// ---------------------------------------------------------------------------
__global__ __launch_bounds__(256) void temporal_attn(
    const float* __restrict__ q, const float* __restrict__ k,
    const float* __restrict__ v, float* __restrict__ out)
{
  int idx = blockIdx.x * 256 + threadIdx.x;
  const int total = B_ * NN * HH * T_;
  if (idx >= total) return;

  int t  = idx % T_;
  int h  = (idx / T_) % HH;
  int n  = (idx / (T_ * HH)) % NN;
  int b  = idx / (T_ * HH * NN);

  const float* qp = q + ((size_t)((b * T_ + t) * NN + n)) * DD + h * HD;
  float qr[HD];
  #pragma unroll
  for (int d = 0; d < HD; ++d) qr[d] = qp[d];

  float o[HD] = {};
  float mrun = -INFINITY, lrun = 0.f;

  for (int tt = 0; tt <= t; ++tt) {
    const float* kp = k + ((size_t)((b * T_ + tt) * NN + n)) * DD + h * HD;
    float s = 0.f;
    #pragma unroll
    for (int d = 0; d < HD; ++d) s += qr[d] * kp[d];
    s *= ATT_SCALE;

    float mnew = fmaxf(mrun, s);
    float corr = __expf(mrun - mnew);
    float p = __expf(s - mnew);
    lrun = lrun * corr + p;
    const float* vp = v + ((size_t)((b * T_ + tt) * NN + n)) * DD + h * HD;
    #pragma unroll
    for (int d = 0; d < HD; ++d) o[d] = o[d] * corr + p * vp[d];
    mrun = mnew;
  }

  float inv = 1.f / lrun;
  float* op = out + ((size_t)((b * T_ + t) * NN + n)) * DD + h * HD;
  #pragma unroll
  for (int d = 0; d < HD; ++d) op[d] = o[d] * inv;
}

// ---------------------------------------------------------------------------
// Fused residual-add + LayerNorm: y = LN(x + r) * w + b. One wave per row.
// ---------------------------------------------------------------------------
__global__ __launch_bounds__(64) void add_ln(
    const float* __restrict__ x, const float* __restrict__ r,
    const float* __restrict__ w, const float* __restrict__ bb,
    float* __restrict__ y)
{
  const size_t row = blockIdx.x;
  const int lane = threadIdx.x;

  const float4 xv = reinterpret_cast<const float4*>(x + row * DD)[lane];
  const float4 rv = reinterpret_cast<const float4*>(r + row * DD)[lane];
  float e[4] = {xv.x + rv.x, xv.y + rv.y, xv.z + rv.z, xv.w + rv.w};

  float s  = e[0] + e[1] + e[2] + e[3];
  float ss = e[0]*e[0] + e[1]*e[1] + e[2]*e[2] + e[3]*e[3];
  #pragma unroll
  for (int off = 32; off > 0; off >>= 1) {
    s  += __shfl_xor(s,  off, 64);
    ss += __shfl_xor(ss, off, 64);
  }
  float mu  = s * (1.f / DD);
  float var = ss * (1.f / DD) - mu * mu;
  float rs  = rsqrtf(var + LN_EPS);

  const float4 wv = reinterpret_cast<const float4*>(w)[lane];
  const float4 bv = reinterpret_cast<const float4*>(bb)[lane];
  float4 yv;
  yv.x = (e[0] - mu) * rs * wv.x + bv.x;
  yv.y = (e[1] - mu) * rs * wv.y + bv.y;
  yv.z = (e[2] - mu) * rs * wv.z + bv.z;
  yv.w = (e[3] - mu) * rs * wv.w + bv.w;
  reinterpret_cast<float4*>(y + row * DD)[lane] = yv;
}

// ---------------------------------------------------------------------------
extern "C" void kernel_launch(void* const* d_in, const int* in_sizes, int n_in,
                              void* d_out, int out_size, void* d_ws, size_t ws_size,
                              hipStream_t stream)
{
  const float* x0   = (const float*)d_in[0];
  const int*   adj  = (const int*)  d_in[1];
  const float* sa_wq = (const float*)d_in[2];
  const float* sa_bq = (const float*)d_in[3];
  const float* sa_wk = (const float*)d_in[4];
  const float* sa_bk = (const float*)d_in[5];
  const float* sa_wv = (const float*)d_in[6];
  const float* sa_bv = (const float*)d_in[7];
  const float* sa_wo = (const float*)d_in[8];
  const float* sa_bo = (const float*)d_in[9];
  const float* sa_lw = (const float*)d_in[10];
  const float* sa_lb = (const float*)d_in[11];
  const float* ta_wq = (const float*)d_in[12];
  const float* ta_bq = (const float*)d_in[13];
  const float* ta_wk = (const float*)d_in[14];
  const float* ta_bk = (const float*)d_in[15];
  const float* ta_wv = (const float*)d_in[16];
  const float* ta_bv = (const float*)d_in[17];
  const float* ta_wo = (const float*)d_in[18];
  const float* ta_bo = (const float*)d_in[19];
  const float* ta_lw = (const float*)d_in[20];
  const float* ta_lb = (const float*)d_in[21];
  const float* f_w1  = (const float*)d_in[22];
  const float* f_b1  = (const float*)d_in[23];
  const float* f_w2  = (const float*)d_in[24];
  const float* f_b2  = (const float*)d_in[25];
  const float* f_lw  = (const float*)d_in[26];
  const float* f_lb  = (const float*)d_in[27];

  float* out = (float*)d_out;
  float* ws  = (float*)d_ws;

  const size_t P = (size_t)MTOK * DD;           // 7,987,200 floats per buffer
  if (ws_size < 7 * P * sizeof(float)) return;  // need ~224 MB scratch

  float* R0 = ws;
  float* R1 = ws + P;
  float* R2 = ws + 2 * P;
  float* R3 = ws + 3 * P;
  float* R4 = ws + 4 * P;
  float* Hb = ws + 3 * P;   // FFN hidden (M x 1024), reuses R3/R4 space in stage C

  dim3 gemm_blk(256);
  auto gemm = [&](const float* A, const float* W, const float* bias, float* C,
                  int Nr, int Kr, int act) {
    dim3 grid((MTOK + BM - 1) / BM, Nr / BN);
    gemm_bias_act<<<grid, gemm_blk, 0, stream>>>(A, W, bias, C, MTOK, Nr, Kr, act);
  };

  // ---- Stage A: spatial attention ----
  gemm(x0, sa_wq, sa_bq, R0, DD, DD, 0);
  gemm(x0, sa_wk, sa_bk, R1, DD, DD, 0);
  gemm(x0, sa_wv, sa_bv, R2, DD, DD, 0);
  spatial_attn<<<dim3(B_ * T_, HH), 384, 0, stream>>>(R0, R1, R2, adj, R3);
  gemm(R3, sa_wo, sa_bo, R4, DD, DD, 0);
  add_ln<<<MTOK, 64, 0, stream>>>(x0, R4, sa_lw, sa_lb, R1);   // x1 -> R1

  // ---- Stage B: temporal attention (causal) ----
  gemm(R1, ta_wq, ta_bq, R0, DD, DD, 0);
  gemm(R1, ta_wk, ta_bk, R2, DD, DD, 0);
  gemm(R1, ta_wv, ta_bv, R3, DD, DD, 0);
  {
    int total = B_ * NN * HH * T_;
    temporal_attn<<<(total + 255) / 256, 256, 0, stream>>>(R0, R2, R3, R4);
  }
  gemm(R4, ta_wo, ta_bo, R0, DD, DD, 0);
  add_ln<<<MTOK, 64, 0, stream>>>(R1, R0, ta_lw, ta_lb, R2);   // x2 -> R2

  // ---- Stage C: FFN ----
  gemm(R2, f_w1, f_b1, Hb, FFD, DD, 1);     // GELU fused
  gemm(Hb, f_w2, f_b2, R0, DD, FFD, 0);
  add_ln<<<MTOK, 64, 0, stream>>>(R2, R0, f_lw, f_lb, out);
}

// Round 3
// 828.763 us; speedup vs baseline: 1.8373x; 1.8373x over previous
//
#include <hip/hip_runtime.h>
#include <hip/hip_bf16.h>
#include <math.h>

#define B_   8
#define T_   12
#define NN   325
#define DD   256
#define HH   8
#define HD   32
#define FFD  1024
#define MTOK (B_*T_*NN)     // 31200 tokens
#define ATT_SCALE 0.17677669529663687f   // 1/sqrt(32)
#define LN_EPS 1e-5f

typedef __attribute__((ext_vector_type(8))) __bf16 bf16x8;
typedef __attribute__((ext_vector_type(4))) float  f32x4;
typedef __attribute__((ext_vector_type(4))) short  short4v;

// async global->LDS, 16B per lane, wave-uniform LDS base + lane*16
#define GLDS(gsrc, ldst) \
  __builtin_amdgcn_global_load_lds((const __attribute__((address_space(1))) void*)(gsrc), \
                                   (__attribute__((address_space(3))) void*)(ldst), 16, 0, 0)

// ---------------------------------------------------------------------------
// bf16 MFMA GEMM (m97 structure): C[M,N] = A[M,K] @ W[K,N] + bias.
// A: bf16 [M,K]. Wt: bf16 [N,K] (pre-transposed). 128x128 tile, BK=32,
// 4 waves (2x2), each wave 64x64 via 4x4 grid of 16x16x32 MFMA.
// mode 0: fp32 out. mode 1: bf16 out with exact GELU (FFN1).
// ---------------------------------------------------------------------------
__global__ __launch_bounds__(256) void gemm_mfma(
    const __hip_bfloat16* __restrict__ A,
    const __hip_bfloat16* __restrict__ Wt,
    const float* __restrict__ bias,
    float* __restrict__ Cf, __hip_bfloat16* __restrict__ Cb,
    int Mr, int Nr, int Kr, int mode)
{
  __shared__ __hip_bfloat16 As[128 * 32];
  __shared__ __hip_bfloat16 Bs[128 * 32];

  const int tid  = threadIdx.x;
  const int w    = tid >> 6;        // wave 0..3
  const int lane = tid & 63;
  const int wr   = w >> 1, wc = w & 1;
  const int m0   = blockIdx.x * 128;
  const int n0   = blockIdx.y * 128;

  f32x4 acc[4][4] = {};

  // staging addressing: per wave 2 chunks of 16 rows for A and for B
  const int srow = w * 32 + (lane >> 2);     // row within tile (chunk 0)
  const int scol = (lane & 3) * 8;           // bf16 col offset (16B per lane)

  int ar0 = m0 + srow;      if (ar0 >= Mr) ar0 = Mr - 1;
  int ar1 = m0 + srow + 16; if (ar1 >= Mr) ar1 = Mr - 1;
  const size_t aOff0 = (size_t)ar0 * Kr + scol;
  const size_t aOff1 = (size_t)ar1 * Kr + scol;
  const size_t bOff0 = (size_t)(n0 + srow) * Kr + scol;
  const size_t bOff1 = (size_t)(n0 + srow + 16) * Kr + scol;
  __hip_bfloat16* ldsA0 = &As[(w * 32) * 32];
  __hip_bfloat16* ldsA1 = &As[(w * 32 + 16) * 32];
  __hip_bfloat16* ldsB0 = &Bs[(w * 32) * 32];
  __hip_bfloat16* ldsB1 = &Bs[(w * 32 + 16) * 32];

  const int lr = lane & 15;
  const int kb = (lane >> 4) * 8;

  for (int k0 = 0; k0 < Kr; k0 += 32) {
    GLDS(&A[aOff0 + k0],  ldsA0);
    GLDS(&A[aOff1 + k0],  ldsA1);
    GLDS(&Wt[bOff0 + k0], ldsB0);
    GLDS(&Wt[bOff1 + k0], ldsB1);
    __syncthreads();   // drains vmcnt before any wave proceeds

    bf16x8 af[4], bfr[4];
    #pragma unroll
    for (int i = 0; i < 4; ++i) {
      af[i]  = *(const bf16x8*)&As[(wr * 64 + i * 16 + lr) * 32 + kb];
      bfr[i] = *(const bf16x8*)&Bs[(wc * 64 + i * 16 + lr) * 32 + kb];
    }
    #pragma unroll
    for (int i = 0; i < 4; ++i)
      #pragma unroll
      for (int j = 0; j < 4; ++j)
        acc[i][j] = __builtin_amdgcn_mfma_f32_16x16x32_bf16(af[i], bfr[j], acc[i][j], 0, 0, 0);
    __syncthreads();
  }

  // epilogue: C/D layout col = lane&15, row = (lane>>4)*4 + q
  const int rg = lane >> 4;
  #pragma unroll
  for (int i = 0; i < 4; ++i) {
    int rowb = m0 + wr * 64 + i * 16 + rg * 4;
    #pragma unroll
    for (int j = 0; j < 4; ++j) {
      int col = n0 + wc * 64 + j * 16 + lr;
      float bv = bias[col];
      #pragma unroll
      for (int q = 0; q < 4; ++q) {
        int gm = rowb + q;
        if (gm >= Mr) continue;
        float c = acc[i][j][q] + bv;
        if (mode == 1) {
          c = 0.5f * c * (1.f + erff(c * 0.70710678118654752f));  // exact GELU
          Cb[(size_t)gm * Nr + col] = __float2bfloat16(c);
        } else {
          Cf[(size_t)gm * Nr + col] = c;
        }
      }
    }
  }
}

// ---------------------------------------------------------------------------
// Weight transpose + convert: Wt[N][K] bf16 <- W[K][N] fp32. 32x32 LDS tiles.
// ---------------------------------------------------------------------------
__global__ __launch_bounds__(256) void wt_cvt(
    const float* __restrict__ W, __hip_bfloat16* __restrict__ Wt, int K, int N)
{
  __shared__ float t[32][33];
  const int n0 = blockIdx.x * 32, k0 = blockIdx.y * 32;
  const int tx = threadIdx.x & 31, ty = threadIdx.x >> 5;   // 32x8
  #pragma unroll
  for (int i = 0; i < 32; i += 8)
    t[ty + i][tx] = W[(size_t)(k0 + ty + i) * N + n0 + tx];
  __syncthreads();
  #pragma unroll
  for (int i = 0; i < 32; i += 8)
    Wt[(size_t)(n0 + ty + i) * K + k0 + tx] = __float2bfloat16(t[tx][ty + i]);
}

// ---------------------------------------------------------------------------
// fp32 -> bf16 convert (4 elems/thread, packed 8B store)
// ---------------------------------------------------------------------------
__global__ __launch_bounds__(256) void cvt_bf16(
    const float* __restrict__ x, __hip_bfloat16* __restrict__ y, int n4)
{
  int i = blockIdx.x * 256 + threadIdx.x;
  if (i >= n4) return;
  float4 v = reinterpret_cast<const float4*>(x)[i];
  union { short4v s; __hip_bfloat16 h[4]; } u;
  u.h[0] = __float2bfloat16(v.x); u.h[1] = __float2bfloat16(v.y);
  u.h[2] = __float2bfloat16(v.z); u.h[3] = __float2bfloat16(v.w);
  reinterpret_cast<short4v*>(y)[i] = u.s;
}

// ---------------------------------------------------------------------------
// Spatial attention (bf16 out), defer-max online softmax (exact).
// ---------------------------------------------------------------------------
__global__ __launch_bounds__(384) void spatial_attn(
    const float* __restrict__ q, const float* __restrict__ k,
    const float* __restrict__ v, const int* __restrict__ adj,
    __hip_bfloat16* __restrict__ out)
{
  const int g = blockIdx.x;    // 0..95
  const int h = blockIdx.y;    // 0..7
  const int l = threadIdx.x;
  if (l >= NN) return;

  const float* qp = q + ((size_t)(g * NN + l)) * DD + h * HD;
  float qr[HD];
  #pragma unroll
  for (int d = 0; d < HD; ++d) qr[d] = qp[d];

  float o[HD] = {};
  float mrun = -INFINITY, lrun = 0.f;
  const int* maskrow = adj + (size_t)l * NN;

  for (int m = 0; m < NN; ++m) {
    const float* kp = k + ((size_t)(g * NN + m)) * DD + h * HD;
    float s = 0.f;
    #pragma unroll
    for (int d = 0; d < HD; ++d) s += qr[d] * kp[d];
    s *= ATT_SCALE;
    if (maskrow[m] == 0) s = -1e30f;

    if (s > mrun) {               // rare after warmup: exact rescale
      float corr = __expf(mrun - s);
      lrun *= corr;
      #pragma unroll
      for (int d = 0; d < HD; ++d) o[d] *= corr;
      mrun = s;
    }
    float p = __expf(s - mrun);
    lrun += p;
    const float* vp = v + ((size_t)(g * NN + m)) * DD + h * HD;
    #pragma unroll
    for (int d = 0; d < HD; ++d) o[d] += p * vp[d];
  }

  float inv = 1.f / lrun;
  __hip_bfloat16* op = out + ((size_t)(g * NN + l)) * DD + h * HD;
  #pragma unroll
  for (int d0 = 0; d0 < HD; d0 += 4) {
    union { short4v s; __hip_bfloat16 h4[4]; } u;
    #pragma unroll
    for (int j = 0; j < 4; ++j) u.h4[j] = __float2bfloat16(o[d0 + j] * inv);
    *reinterpret_cast<short4v*>(op + d0) = u.s;
  }
}

// ---------------------------------------------------------------------------
// Temporal attention (causal, T=12), bf16 out, defer-max.
// ---------------------------------------------------------------------------
__global__ __launch_bounds__(256) void temporal_attn(
    const float* __restrict__ q, const float* __restrict__ k,
    const float* __restrict__ v, __hip_bfloat16* __restrict__ out)
{
  int idx = blockIdx.x * 256 + threadIdx.x;
  const int total = B_ * NN * HH * T_;
  if (idx >= total) return;

  int t  = idx % T_;
  int h  = (idx / T_) % HH;
  int n  = (idx / (T_ * HH)) % NN;
  int b  = idx / (T_ * HH * NN);

  const float* qp = q + ((size_t)((b * T_ + t) * NN + n)) * DD + h * HD;
  float qr[HD];
  #pragma unroll
  for (int d = 0; d < HD; ++d) qr[d] = qp[d];

  float o[HD] = {};
  float mrun = -INFINITY, lrun = 0.f;

  for (int tt = 0; tt <= t; ++tt) {
    const float* kp = k + ((size_t)((b * T_ + tt) * NN + n)) * DD + h * HD;
    float s = 0.f;
    #pragma unroll
    for (int d = 0; d < HD; ++d) s += qr[d] * kp[d];
    s *= ATT_SCALE;

    if (s > mrun) {
      float corr = __expf(mrun - s);
      lrun *= corr;
      #pragma unroll
      for (int d = 0; d < HD; ++d) o[d] *= corr;
      mrun = s;
    }
    float p = __expf(s - mrun);
    lrun += p;
    const float* vp = v + ((size_t)((b * T_ + tt) * NN + n)) * DD + h * HD;
    #pragma unroll
    for (int d = 0; d < HD; ++d) o[d] += p * vp[d];
  }

  float inv = 1.f / lrun;
  __hip_bfloat16* op = out + ((size_t)((b * T_ + t) * NN + n)) * DD + h * HD;
  #pragma unroll
  for (int d0 = 0; d0 < HD; d0 += 4) {
    union { short4v s; __hip_bfloat16 h4[4]; } u;
    #pragma unroll
    for (int j = 0; j < 4; ++j) u.h4[j] = __float2bfloat16(o[d0 + j] * inv);
    *reinterpret_cast<short4v*>(op + d0) = u.s;
  }
}

// ---------------------------------------------------------------------------
// Fused residual-add + LayerNorm; fp32 out + optional bf16 copy. 1 wave/row.
// ---------------------------------------------------------------------------
__global__ __launch_bounds__(64) void add_ln(
    const float* __restrict__ x, const float* __restrict__ r,
    const float* __restrict__ w, const float* __restrict__ bb,
    float* __restrict__ y, __hip_bfloat16* __restrict__ ybf)
{
  const size_t row = blockIdx.x;
  const int lane = threadIdx.x;

  const float4 xv = reinterpret_cast<const float4*>(x + row * DD)[lane];
  const float4 rv = reinterpret_cast<const float4*>(r + row * DD)[lane];
  float e[4] = {xv.x + rv.x, xv.y + rv.y, xv.z + rv.z, xv.w + rv.w};

  float s  = e[0] + e[1] + e[2] + e[3];
  float ss = e[0]*e[0] + e[1]*e[1] + e[2]*e[2] + e[3]*e[3];
  #pragma unroll
  for (int off = 32; off > 0; off >>= 1) {
    s  += __shfl_xor(s,  off, 64);
    ss += __shfl_xor(ss, off, 64);
  }
  float mu  = s * (1.f / DD);
  float var = ss * (1.f / DD) - mu * mu;
  float rs  = rsqrtf(var + LN_EPS);

  const float4 wv = reinterpret_cast<const float4*>(w)[lane];
  const float4 bv = reinterpret_cast<const float4*>(bb)[lane];
  float o0 = (e[0] - mu) * rs * wv.x + bv.x;
  float o1 = (e[1] - mu) * rs * wv.y + bv.y;
  float o2 = (e[2] - mu) * rs * wv.z + bv.z;
  float o3 = (e[3] - mu) * rs * wv.w + bv.w;
  float4 yv = {o0, o1, o2, o3};
  reinterpret_cast<float4*>(y + row * DD)[lane] = yv;
  if (ybf) {
    union { short4v s4; __hip_bfloat16 h4[4]; } u;
    u.h4[0] = __float2bfloat16(o0); u.h4[1] = __float2bfloat16(o1);
    u.h4[2] = __float2bfloat16(o2); u.h4[3] = __float2bfloat16(o3);
    reinterpret_cast<short4v*>(ybf + row * DD)[lane] = u.s4;
  }
}

// ---------------------------------------------------------------------------
extern "C" void kernel_launch(void* const* d_in, const int* in_sizes, int n_in,
                              void* d_out, int out_size, void* d_ws, size_t ws_size,
                              hipStream_t stream)
{
  const float* x0   = (const float*)d_in[0];
  const int*   adj  = (const int*)  d_in[1];
  const float* sa_wq = (const float*)d_in[2];
  const float* sa_bq = (const float*)d_in[3];
  const float* sa_wk = (const float*)d_in[4];
  const float* sa_bk = (const float*)d_in[5];
  const float* sa_wv = (const float*)d_in[6];
  const float* sa_bv = (const float*)d_in[7];
  const float* sa_wo = (const float*)d_in[8];
  const float* sa_bo = (const float*)d_in[9];
  const float* sa_lw = (const float*)d_in[10];
  const float* sa_lb = (const float*)d_in[11];
  const float* ta_wq = (const float*)d_in[12];
  const float* ta_bq = (const float*)d_in[13];
  const float* ta_wk = (const float*)d_in[14];
  const float* ta_bk = (const float*)d_in[15];
  const float* ta_wv = (const float*)d_in[16];
  const float* ta_bv = (const float*)d_in[17];
  const float* ta_wo = (const float*)d_in[18];
  const float* ta_bo = (const float*)d_in[19];
  const float* ta_lw = (const float*)d_in[20];
  const float* ta_lb = (const float*)d_in[21];
  const float* f_w1  = (const float*)d_in[22];
  const float* f_b1  = (const float*)d_in[23];
  const float* f_w2  = (const float*)d_in[24];
  const float* f_b2  = (const float*)d_in[25];
  const float* f_lw  = (const float*)d_in[26];
  const float* f_lb  = (const float*)d_in[27];

  float* out = (float*)d_out;
  float* ws  = (float*)d_ws;

  const size_t P = (size_t)MTOK * DD;           // 7,987,200 floats
  if (ws_size < 7 * P * sizeof(float)) return;

  float* R0 = ws;
  float* R1 = ws + P;
  float* R2 = ws + 2 * P;
  float* R3 = ws + 3 * P;
  float* R4 = ws + 4 * P;
  __hip_bfloat16* X0b  = (__hip_bfloat16*)(ws + 5 * P);        // also X2b later
  __hip_bfloat16* X1b  = (__hip_bfloat16*)(ws + 5 * P + P / 2);
  __hip_bfloat16* ATTb = (__hip_bfloat16*)(ws + 6 * P);
  __hip_bfloat16* Wb   = (__hip_bfloat16*)(ws + 6 * P + P / 2);
  __hip_bfloat16* HIDb = (__hip_bfloat16*)(ws + P);            // reuses R1+R2 in stage C

  // transposed bf16 weights
  __hip_bfloat16* sa_wq_t = Wb;
  __hip_bfloat16* sa_wk_t = Wb + 65536;
  __hip_bfloat16* sa_wv_t = Wb + 131072;
  __hip_bfloat16* sa_wo_t = Wb + 196608;
  __hip_bfloat16* ta_wq_t = Wb + 262144;
  __hip_bfloat16* ta_wk_t = Wb + 327680;
  __hip_bfloat16* ta_wv_t = Wb + 393216;
  __hip_bfloat16* ta_wo_t = Wb + 458752;
  __hip_bfloat16* f_w1_t  = Wb + 524288;   // [1024][256]
  __hip_bfloat16* f_w2_t  = Wb + 786432;   // [256][1024]

  // ---- prep: weight transpose+convert, x0 -> bf16 ----
  wt_cvt<<<dim3(DD/32, DD/32), 256, 0, stream>>>(sa_wq, sa_wq_t, DD, DD);
  wt_cvt<<<dim3(DD/32, DD/32), 256, 0, stream>>>(sa_wk, sa_wk_t, DD, DD);
  wt_cvt<<<dim3(DD/32, DD/32), 256, 0, stream>>>(sa_wv, sa_wv_t, DD, DD);
  wt_cvt<<<dim3(DD/32, DD/32), 256, 0, stream>>>(sa_wo, sa_wo_t, DD, DD);
  wt_cvt<<<dim3(DD/32, DD/32), 256, 0, stream>>>(ta_wq, ta_wq_t, DD, DD);
  wt_cvt<<<dim3(DD/32, DD/32), 256, 0, stream>>>(ta_wk, ta_wk_t, DD, DD);
  wt_cvt<<<dim3(DD/32, DD/32), 256, 0, stream>>>(ta_wv, ta_wv_t, DD, DD);
  wt_cvt<<<dim3(DD/32, DD/32), 256, 0, stream>>>(ta_wo, ta_wo_t, DD, DD);
  wt_cvt<<<dim3(FFD/32, DD/32), 256, 0, stream>>>(f_w1, f_w1_t, DD, FFD);
  wt_cvt<<<dim3(DD/32, FFD/32), 256, 0, stream>>>(f_w2, f_w2_t, FFD, DD);
  {
    int n4 = (int)(P / 4);
    cvt_bf16<<<(n4 + 255) / 256, 256, 0, stream>>>(x0, X0b, n4);
  }

  auto gemm = [&](const __hip_bfloat16* A, const __hip_bfloat16* Wt, const float* bias,
                  float* Cf, __hip_bfloat16* Cb, int Nr, int Kr, int mode) {
    dim3 grid((MTOK + 127) / 128, Nr / 128);
    gemm_mfma<<<grid, 256, 0, stream>>>(A, Wt, bias, Cf, Cb, MTOK, Nr, Kr, mode);
  };

  // ---- Stage A: spatial attention ----
  gemm(X0b, sa_wq_t, sa_bq, R0, nullptr, DD, DD, 0);
  gemm(X0b, sa_wk_t, sa_bk, R1, nullptr, DD, DD, 0);
  gemm(X0b, sa_wv_t, sa_bv, R2, nullptr, DD, DD, 0);
  spatial_attn<<<dim3(B_ * T_, HH), 384, 0, stream>>>(R0, R1, R2, adj, ATTb);
  gemm(ATTb, sa_wo_t, sa_bo, R3, nullptr, DD, DD, 0);
  add_ln<<<MTOK, 64, 0, stream>>>(x0, R3, sa_lw, sa_lb, R4, X1b);   // x1: R4 + X1b

  // ---- Stage B: temporal attention ----
  gemm(X1b, ta_wq_t, ta_bq, R0, nullptr, DD, DD, 0);
  gemm(X1b, ta_wk_t, ta_bk, R1, nullptr, DD, DD, 0);
  gemm(X1b, ta_wv_t, ta_bv, R2, nullptr, DD, DD, 0);
  {
    int total = B_ * NN * HH * T_;
    temporal_attn<<<(total + 255) / 256, 256, 0, stream>>>(R0, R1, R2, ATTb);
  }
  gemm(ATTb, ta_wo_t, ta_bo, R3, nullptr, DD, DD, 0);
  add_ln<<<MTOK, 64, 0, stream>>>(R4, R3, ta_lw, ta_lb, R0, X0b);   // x2: R0 + X0b (X0b free)

  // ---- Stage C: FFN ----
  gemm(X0b, f_w1_t, f_b1, nullptr, HIDb, FFD, DD, 1);               // GELU, bf16 hidden
  gemm(HIDb, f_w2_t, f_b2, R3, nullptr, DD, FFD, 0);
  add_ln<<<MTOK, 64, 0, stream>>>(R0, R3, f_lw, f_lb, out, nullptr);
}

// Round 5
// 467.311 us; speedup vs baseline: 3.2585x; 1.7735x over previous
//
#include <hip/hip_runtime.h>
#include <hip/hip_bf16.h>
#include <math.h>

#define B_   8
#define T_   12
#define NN   325
#define DD   256
#define HH   8
#define HD   32
#define FFD  1024
#define MTOK (B_*T_*NN)     // 31200 tokens
#define ATT_SCALE 0.17677669529663687f   // 1/sqrt(32)
#define LN_EPS 1e-5f
#define NEG_BIG (-1e30f)

typedef __attribute__((ext_vector_type(8))) __bf16 bf16x8;
typedef __attribute__((ext_vector_type(4))) float  f32x4;
typedef __attribute__((ext_vector_type(4))) short  shortx4;

// 16x16x16 bf16 MFMA (ISA: v_mfma_f32_16x16x16_bf16; A/B = 4 bf16/lane)
#if __has_builtin(__builtin_amdgcn_mfma_f32_16x16x16bf16_1k)
#define MFMA16(a,b,c) __builtin_amdgcn_mfma_f32_16x16x16bf16_1k((a),(b),(c),0,0,0)
#else
static __device__ inline f32x4 mfma16_fn(shortx4 a, shortx4 b, f32x4 c) {
  f32x4 d;
  asm volatile("v_mfma_f32_16x16x16_bf16 %0, %1, %2, %3"
               : "=v"(d) : "v"(a), "v"(b), "v"(c));
  return d;
}
#define MFMA16(a,b,c) mfma16_fn((a),(b),(c))
#endif

// async global->LDS, 16B per lane, wave-uniform LDS base + lane*16
#define GLDS(gsrc, ldst) \
  __builtin_amdgcn_global_load_lds((const __attribute__((address_space(1))) void*)(gsrc), \
                                   (__attribute__((address_space(3))) void*)(ldst), 16, 0, 0)

// ---------------------------------------------------------------------------
// bf16 MFMA GEMM (m97 structure): C[M,N] = A[M,K] @ W[K,N] + bias.
// A: bf16 [M,K]. Wt: bf16 [N,K]. 128x128 tile, BK=32, 4 waves.
// mode 0: fp32 out. mode 1: bf16 out + exact GELU. mode 2: bf16 out.
// ---------------------------------------------------------------------------
__global__ __launch_bounds__(256) void gemm_mfma(
    const __hip_bfloat16* __restrict__ A,
    const __hip_bfloat16* __restrict__ Wt,
    const float* __restrict__ bias,
    float* __restrict__ Cf, __hip_bfloat16* __restrict__ Cb,
    int Mr, int Nr, int Kr, int mode)
{
  __shared__ __hip_bfloat16 As[128 * 32];
  __shared__ __hip_bfloat16 Bs[128 * 32];

  const int tid  = threadIdx.x;
  const int w    = tid >> 6;
  const int lane = tid & 63;
  const int wr   = w >> 1, wc = w & 1;
  const int m0   = blockIdx.x * 128;
  const int n0   = blockIdx.y * 128;

  f32x4 acc[4][4] = {};

  const int srow = w * 32 + (lane >> 2);
  const int scol = (lane & 3) * 8;

  int ar0 = m0 + srow;      if (ar0 >= Mr) ar0 = Mr - 1;
  int ar1 = m0 + srow + 16; if (ar1 >= Mr) ar1 = Mr - 1;
  const size_t aOff0 = (size_t)ar0 * Kr + scol;
  const size_t aOff1 = (size_t)ar1 * Kr + scol;
  const size_t bOff0 = (size_t)(n0 + srow) * Kr + scol;
  const size_t bOff1 = (size_t)(n0 + srow + 16) * Kr + scol;
  __hip_bfloat16* ldsA0 = &As[(w * 32) * 32];
  __hip_bfloat16* ldsA1 = &As[(w * 32 + 16) * 32];
  __hip_bfloat16* ldsB0 = &Bs[(w * 32) * 32];
  __hip_bfloat16* ldsB1 = &Bs[(w * 32 + 16) * 32];

  const int lr = lane & 15;
  const int kb = (lane >> 4) * 8;

  for (int k0 = 0; k0 < Kr; k0 += 32) {
    GLDS(&A[aOff0 + k0],  ldsA0);
    GLDS(&A[aOff1 + k0],  ldsA1);
    GLDS(&Wt[bOff0 + k0], ldsB0);
    GLDS(&Wt[bOff1 + k0], ldsB1);
    __syncthreads();

    bf16x8 af[4], bfr[4];
    #pragma unroll
    for (int i = 0; i < 4; ++i) {
      af[i]  = *(const bf16x8*)&As[(wr * 64 + i * 16 + lr) * 32 + kb];
      bfr[i] = *(const bf16x8*)&Bs[(wc * 64 + i * 16 + lr) * 32 + kb];
    }
    #pragma unroll
    for (int i = 0; i < 4; ++i)
      #pragma unroll
      for (int j = 0; j < 4; ++j)
        acc[i][j] = __builtin_amdgcn_mfma_f32_16x16x32_bf16(af[i], bfr[j], acc[i][j], 0, 0, 0);
    __syncthreads();
  }

  const int rg = lane >> 4;
  #pragma unroll
  for (int i = 0; i < 4; ++i) {
    int rowb = m0 + wr * 64 + i * 16 + rg * 4;
    #pragma unroll
    for (int j = 0; j < 4; ++j) {
      int col = n0 + wc * 64 + j * 16 + lr;
      float bv = bias[col];
      #pragma unroll
      for (int q = 0; q < 4; ++q) {
        int gm = rowb + q;
        if (gm >= Mr) continue;
        float c = acc[i][j][q] + bv;
        if (mode == 0) {
          Cf[(size_t)gm * Nr + col] = c;
        } else {
          if (mode == 1) c = 0.5f * c * (1.f + erff(c * 0.70710678118654752f));
          Cb[(size_t)gm * Nr + col] = __float2bfloat16(c);
        }
      }
    }
  }
}

// ---------------------------------------------------------------------------
// Weight transpose + convert: Wt[N][K] bf16 <- W[K][N] fp32.
// ---------------------------------------------------------------------------
__global__ __launch_bounds__(256) void wt_cvt(
    const float* __restrict__ W, __hip_bfloat16* __restrict__ Wt, int K, int N)
{
  __shared__ float t[32][33];
  const int n0 = blockIdx.x * 32, k0 = blockIdx.y * 32;
  const int tx = threadIdx.x & 31, ty = threadIdx.x >> 5;
  #pragma unroll
  for (int i = 0; i < 32; i += 8)
    t[ty + i][tx] = W[(size_t)(k0 + ty + i) * N + n0 + tx];
  __syncthreads();
  #pragma unroll
  for (int i = 0; i < 32; i += 8)
    Wt[(size_t)(n0 + ty + i) * K + k0 + tx] = __float2bfloat16(t[tx][ty + i]);
}

__global__ __launch_bounds__(256) void cvt_bf16(
    const float* __restrict__ x, __hip_bfloat16* __restrict__ y, int n4)
{
  int i = blockIdx.x * 256 + threadIdx.x;
  if (i >= n4) return;
  float4 v = reinterpret_cast<const float4*>(x)[i];
  union { shortx4 s; __hip_bfloat16 h[4]; } u;
  u.h[0] = __float2bfloat16(v.x); u.h[1] = __float2bfloat16(v.y);
  u.h[2] = __float2bfloat16(v.z); u.h[3] = __float2bfloat16(v.w);
  reinterpret_cast<shortx4*>(y)[i] = u.s;
}

// ---------------------------------------------------------------------------
// Pack adjacency mask to bits: mb[l][w] bit b = (adj[l][w*32+b] != 0), 11 words/row.
// ---------------------------------------------------------------------------
__global__ __launch_bounds__(256) void maskpack(
    const int* __restrict__ adj, unsigned int* __restrict__ mb)
{
  int idx = blockIdx.x * 256 + threadIdx.x;
  if (idx >= NN * 11) return;
  int l = idx / 11, w = idx % 11;
  unsigned int bits = 0;
  #pragma unroll 4
  for (int b = 0; b < 32; ++b) {
    int m = w * 32 + b;
    if (m < NN && adj[l * NN + m] != 0) bits |= (1u << b);
  }
  mb[idx] = bits;
}

// ---------------------------------------------------------------------------
// MFMA spatial attention. One workgroup per (g, h); 4 waves split 21 Q-tiles.
// S^T = mfma_16x16x32(K, Q): lane holds 4 keys for ONE query (col=lane&15).
// C-layout == 16x16x16 B-layout, so softmax'd P feeds PV MFMA in-register.
// O^T = V^T @ P^T accumulated over 21 key-tiles; V^T staged in LDS (ushort bits).
// ---------------------------------------------------------------------------
__global__ __launch_bounds__(256) void spatial_attn_mfma(
    const __hip_bfloat16* __restrict__ Qg,
    const __hip_bfloat16* __restrict__ Kg,
    const __hip_bfloat16* __restrict__ Vg,
    const unsigned int* __restrict__ mb,
    __hip_bfloat16* __restrict__ out)
{
  constexpr int KP = 40;    // K_lds pitch (bf16): 80B rows -> ~2-way banks (free)
  constexpr int VP = 340;   // V^T pitch: 680B rows -> stride 170 dwords, 2-way (free)
  __shared__ unsigned short Kl[336 * KP];  // [key][d] bf16 bits, 26880 B
  __shared__ unsigned short Vt[32 * VP];   // [d][key] bf16 bits, 21760 B

  const int g = blockIdx.x, h = blockIdx.y;
  const int tid = threadIdx.x;
  const int w = tid >> 6, lane = tid & 63;
  const int lq = lane & 15, lg = lane >> 4;

  const size_t base = ((size_t)g * NN) * DD + (size_t)h * HD;

  // zero phantom V^T columns (keys 325..339) so p=0 never meets garbage
  for (int idx = tid; idx < 32 * (VP - NN); idx += 256) {
    int d = idx / (VP - NN), kk = NN + idx % (VP - NN);
    Vt[d * VP + kk] = 0;
  }
  // stage K [325][32] and V^T [32][325] (bit-copy via unions; no bf16 ctor)
  for (int idx = tid; idx < NN * 4; idx += 256) {
    int row = idx >> 2, cc = (idx & 3) * 8;
    union { bf16x8 v; unsigned short u[8]; } kv, vv;
    kv.v = *(const bf16x8*)&Kg[base + (size_t)row * DD + cc];
    *(bf16x8*)&Kl[row * KP + cc] = kv.v;
    vv.v = *(const bf16x8*)&Vg[base + (size_t)row * DD + cc];
    #pragma unroll
    for (int j = 0; j < 8; ++j) Vt[(cc + j) * VP + row] = vv.u[j];
  }
  __syncthreads();

  for (int qt = w; qt < 21; qt += 4) {
    const int query = qt * 16 + lq;
    const int qc = query < NN ? query : NN - 1;
    // Q frag (B-operand): col=lane&15 -> query, k=(lane>>4)*8+j -> d
    const bf16x8 qf = *(const bf16x8*)&Qg[base + (size_t)qc * DD + lg * 8];
    const unsigned int* mrow = &mb[qc * 11];

    f32x4 accL = {0.f, 0.f, 0.f, 0.f};   // O^T d = lg*4+q      (0..15)
    f32x4 accH = {0.f, 0.f, 0.f, 0.f};   // O^T d = 16+lg*4+q   (16..31)
    float mrun = -INFINITY, lrun = 0.f;

    for (int t = 0; t < 21; ++t) {
      // K frag (A-operand): row=lane&15 -> key, k-chunk=(lane>>4)*8
      bf16x8 kf = *(const bf16x8*)&Kl[(t * 16 + lq) * KP + lg * 8];
      f32x4 st = __builtin_amdgcn_mfma_f32_16x16x32_bf16(
          kf, qf, (f32x4){0.f, 0.f, 0.f, 0.f}, 0, 0, 0);
      // st[q] = S^T[key = t*16 + lg*4 + q][query]
      const unsigned int mw = mrow[t >> 1];
      const int kbase = t * 16 + lg * 4;
      const int bbase = (t & 1) * 16 + lg * 4;
      float s[4];
      #pragma unroll
      for (int q = 0; q < 4; ++q) {
        float fill = (kbase + q < NN) ? NEG_BIG : -INFINITY;  // phantom -> p=0
        s[q] = ((mw >> (bbase + q)) & 1u) ? st[q] * ATT_SCALE : fill;
      }
      // row (query) reduction across the 4 lane-groups
      float tmax = fmaxf(fmaxf(s[0], s[1]), fmaxf(s[2], s[3]));
      tmax = fmaxf(tmax, __shfl_xor(tmax, 16));
      tmax = fmaxf(tmax, __shfl_xor(tmax, 32));
      const float mnew = fmaxf(mrun, tmax);
      const float corr = __expf(mrun - mnew);   // exp(-inf)=0 on first tile
      float p0 = __expf(s[0] - mnew), p1 = __expf(s[1] - mnew);
      float p2 = __expf(s[2] - mnew), p3 = __expf(s[3] - mnew);
      float ps = p0 + p1 + p2 + p3;
      ps += __shfl_xor(ps, 16);
      ps += __shfl_xor(ps, 32);
      lrun = lrun * corr + ps;
      mrun = mnew;
      accL *= corr; accH *= corr;
      // P -> bf16 B-fragment (C-layout == x16 B-layout: no transpose)
      union { shortx4 s4; __hip_bfloat16 hh[4]; } up;
      up.hh[0] = __float2bfloat16(p0); up.hh[1] = __float2bfloat16(p1);
      up.hh[2] = __float2bfloat16(p2); up.hh[3] = __float2bfloat16(p3);
      // V^T frags (A-operand): row=lane&15 -> d, k=(lane>>4)*4+j -> key
      shortx4 vaL = *(const shortx4*)&Vt[lq * VP + kbase];
      shortx4 vaH = *(const shortx4*)&Vt[(lq + 16) * VP + kbase];
      accL = MFMA16(vaL, up.s4, accL);
      accH = MFMA16(vaH, up.s4, accH);
    }

    if (query < NN) {
      const float inv = 1.f / lrun;
      const size_t ob = ((size_t)(g * NN + query)) * DD + (size_t)h * HD;
      union { shortx4 s4; __hip_bfloat16 hh[4]; } uL, uH;
      #pragma unroll
      for (int q = 0; q < 4; ++q) {
        uL.hh[q] = __float2bfloat16(accL[q] * inv);
        uH.hh[q] = __float2bfloat16(accH[q] * inv);
      }
      *(shortx4*)&out[ob + lg * 4]      = uL.s4;
      *(shortx4*)&out[ob + 16 + lg * 4] = uH.s4;
    }
  }
}

// ---------------------------------------------------------------------------
// Temporal attention (causal, T=12): thread per (b,n,h,t), plain online softmax.
// ---------------------------------------------------------------------------
__global__ __launch_bounds__(256) void temporal_attn(
    const float* __restrict__ q, const float* __restrict__ k,
    const float* __restrict__ v, __hip_bfloat16* __restrict__ out)
{
  int idx = blockIdx.x * 256 + threadIdx.x;
  const int total = B_ * NN * HH * T_;
  if (idx >= total) return;

  int t  = idx % T_;
  int h  = (idx / T_) % HH;
  int n  = (idx / (T_ * HH)) % NN;
  int b  = idx / (T_ * HH * NN);

  const float* qp = q + ((size_t)((b * T_ + t) * NN + n)) * DD + h * HD;
  float qr[HD];
  #pragma unroll
  for (int d = 0; d < HD; ++d) qr[d] = qp[d];

  float o[HD] = {};
  float mrun = -INFINITY, lrun = 0.f;

  for (int tt = 0; tt <= t; ++tt) {
    const float* kp = k + ((size_t)((b * T_ + tt) * NN + n)) * DD + h * HD;
    float s = 0.f;
    #pragma unroll
    for (int d = 0; d < HD; ++d) s += qr[d] * kp[d];
    s *= ATT_SCALE;

    float mnew = fmaxf(mrun, s);
    float corr = __expf(mrun - mnew);
    float p = __expf(s - mnew);
    lrun = lrun * corr + p;
    const float* vp = v + ((size_t)((b * T_ + tt) * NN + n)) * DD + h * HD;
    #pragma unroll
    for (int d = 0; d < HD; ++d) o[d] = o[d] * corr + p * vp[d];
    mrun = mnew;
  }

  float inv = 1.f / lrun;
  __hip_bfloat16* op = out + ((size_t)((b * T_ + t) * NN + n)) * DD + h * HD;
  #pragma unroll
  for (int d0 = 0; d0 < HD; d0 += 4) {
    union { shortx4 s; __hip_bfloat16 h4[4]; } u;
    #pragma unroll
    for (int j = 0; j < 4; ++j) u.h4[j] = __float2bfloat16(o[d0 + j] * inv);
    *reinterpret_cast<shortx4*>(op + d0) = u.s;
  }
}

// ---------------------------------------------------------------------------
// Fused residual-add + LayerNorm; fp32 out + optional bf16 copy. 1 wave/row.
// ---------------------------------------------------------------------------
__global__ __launch_bounds__(64) void add_ln(
    const float* __restrict__ x, const float* __restrict__ r,
    const float* __restrict__ w, const float* __restrict__ bb,
    float* __restrict__ y, __hip_bfloat16* __restrict__ ybf)
{
  const size_t row = blockIdx.x;
  const int lane = threadIdx.x;

  const float4 xv = reinterpret_cast<const float4*>(x + row * DD)[lane];
  const float4 rv = reinterpret_cast<const float4*>(r + row * DD)[lane];
  float e[4] = {xv.x + rv.x, xv.y + rv.y, xv.z + rv.z, xv.w + rv.w};

  float s  = e[0] + e[1] + e[2] + e[3];
  float ss = e[0]*e[0] + e[1]*e[1] + e[2]*e[2] + e[3]*e[3];
  #pragma unroll
  for (int off = 32; off > 0; off >>= 1) {
    s  += __shfl_xor(s,  off, 64);
    ss += __shfl_xor(ss, off, 64);
  }
  float mu  = s * (1.f / DD);
  float var = ss * (1.f / DD) - mu * mu;
  float rs  = rsqrtf(var + LN_EPS);

  const float4 wv = reinterpret_cast<const float4*>(w)[lane];
  const float4 bv = reinterpret_cast<const float4*>(bb)[lane];
  float o0 = (e[0] - mu) * rs * wv.x + bv.x;
  float o1 = (e[1] - mu) * rs * wv.y + bv.y;
  float o2 = (e[2] - mu) * rs * wv.z + bv.z;
  float o3 = (e[3] - mu) * rs * wv.w + bv.w;
  float4 yv = {o0, o1, o2, o3};
  reinterpret_cast<float4*>(y + row * DD)[lane] = yv;
  if (ybf) {
    union { shortx4 s4; __hip_bfloat16 h4[4]; } u;
    u.h4[0] = __float2bfloat16(o0); u.h4[1] = __float2bfloat16(o1);
    u.h4[2] = __float2bfloat16(o2); u.h4[3] = __float2bfloat16(o3);
    reinterpret_cast<shortx4*>(ybf + row * DD)[lane] = u.s4;
  }
}

// ---------------------------------------------------------------------------
extern "C" void kernel_launch(void* const* d_in, const int* in_sizes, int n_in,
                              void* d_out, int out_size, void* d_ws, size_t ws_size,
                              hipStream_t stream)
{
  const float* x0   = (const float*)d_in[0];
  const int*   adj  = (const int*)  d_in[1];
  const float* sa_wq = (const float*)d_in[2];
  const float* sa_bq = (const float*)d_in[3];
  const float* sa_wk = (const float*)d_in[4];
  const float* sa_bk = (const float*)d_in[5];
  const float* sa_wv = (const float*)d_in[6];
  const float* sa_bv = (const float*)d_in[7];
  const float* sa_wo = (const float*)d_in[8];
  const float* sa_bo = (const float*)d_in[9];
  const float* sa_lw = (const float*)d_in[10];
  const float* sa_lb = (const float*)d_in[11];
  const float* ta_wq = (const float*)d_in[12];
  const float* ta_bq = (const float*)d_in[13];
  const float* ta_wk = (const float*)d_in[14];
  const float* ta_bk = (const float*)d_in[15];
  const float* ta_wv = (const float*)d_in[16];
  const float* ta_bv = (const float*)d_in[17];
  const float* ta_wo = (const float*)d_in[18];
  const float* ta_bo = (const float*)d_in[19];
  const float* ta_lw = (const float*)d_in[20];
  const float* ta_lb = (const float*)d_in[21];
  const float* f_w1  = (const float*)d_in[22];
  const float* f_b1  = (const float*)d_in[23];
  const float* f_w2  = (const float*)d_in[24];
  const float* f_b2  = (const float*)d_in[25];
  const float* f_lw  = (const float*)d_in[26];
  const float* f_lb  = (const float*)d_in[27];

  float* out = (float*)d_out;
  float* ws  = (float*)d_ws;

  const size_t P = (size_t)MTOK * DD;           // 7,987,200 floats
  if (ws_size < 7 * P * sizeof(float)) return;

  float* R0 = ws;
  float* R1 = ws + P;
  float* R2 = ws + 2 * P;
  float* R3 = ws + 3 * P;
  float* R4 = ws + 4 * P;
  __hip_bfloat16* X0b  = (__hip_bfloat16*)(ws + 5 * P);
  __hip_bfloat16* X1b  = (__hip_bfloat16*)(ws + 5 * P + P / 2);
  __hip_bfloat16* ATTb = (__hip_bfloat16*)(ws + 6 * P);
  __hip_bfloat16* Wb   = (__hip_bfloat16*)(ws + 6 * P + P / 2);
  __hip_bfloat16* HIDb = (__hip_bfloat16*)(ws + P);      // stage C: reuses R1+R2
  // bf16 QKV for spatial attention reuse R0/R1/R2 regions during stage A
  __hip_bfloat16* Qb = (__hip_bfloat16*)R0;
  __hip_bfloat16* Kb = (__hip_bfloat16*)R1;
  __hip_bfloat16* Vb = (__hip_bfloat16*)R2;

  // transposed bf16 weights
  __hip_bfloat16* sa_wq_t = Wb;
  __hip_bfloat16* sa_wk_t = Wb + 65536;
  __hip_bfloat16* sa_wv_t = Wb + 131072;
  __hip_bfloat16* sa_wo_t = Wb + 196608;
  __hip_bfloat16* ta_wq_t = Wb + 262144;
  __hip_bfloat16* ta_wk_t = Wb + 327680;
  __hip_bfloat16* ta_wv_t = Wb + 393216;
  __hip_bfloat16* ta_wo_t = Wb + 458752;
  __hip_bfloat16* f_w1_t  = Wb + 524288;   // [1024][256]
  __hip_bfloat16* f_w2_t  = Wb + 786432;   // [256][1024]
  unsigned int*   MB      = (unsigned int*)(Wb + 1048576);  // 325*11 words

  // ---- prep ----
  wt_cvt<<<dim3(DD/32, DD/32), 256, 0, stream>>>(sa_wq, sa_wq_t, DD, DD);
  wt_cvt<<<dim3(DD/32, DD/32), 256, 0, stream>>>(sa_wk, sa_wk_t, DD, DD);
  wt_cvt<<<dim3(DD/32, DD/32), 256, 0, stream>>>(sa_wv, sa_wv_t, DD, DD);
  wt_cvt<<<dim3(DD/32, DD/32), 256, 0, stream>>>(sa_wo, sa_wo_t, DD, DD);
  wt_cvt<<<dim3(DD/32, DD/32), 256, 0, stream>>>(ta_wq, ta_wq_t, DD, DD);
  wt_cvt<<<dim3(DD/32, DD/32), 256, 0, stream>>>(ta_wk, ta_wk_t, DD, DD);
  wt_cvt<<<dim3(DD/32, DD/32), 256, 0, stream>>>(ta_wv, ta_wv_t, DD, DD);
  wt_cvt<<<dim3(DD/32, DD/32), 256, 0, stream>>>(ta_wo, ta_wo_t, DD, DD);
  wt_cvt<<<dim3(FFD/32, DD/32), 256, 0, stream>>>(f_w1, f_w1_t, DD, FFD);
  wt_cvt<<<dim3(DD/32, FFD/32), 256, 0, stream>>>(f_w2, f_w2_t, FFD, DD);
  maskpack<<<(NN * 11 + 255) / 256, 256, 0, stream>>>(adj, MB);
  {
    int n4 = (int)(P / 4);
    cvt_bf16<<<(n4 + 255) / 256, 256, 0, stream>>>(x0, X0b, n4);
  }

  auto gemm = [&](const __hip_bfloat16* A, const __hip_bfloat16* Wt, const float* bias,
                  float* Cf, __hip_bfloat16* Cb, int Nr, int Kr, int mode) {
    dim3 grid((MTOK + 127) / 128, Nr / 128);
    gemm_mfma<<<grid, 256, 0, stream>>>(A, Wt, bias, Cf, Cb, MTOK, Nr, Kr, mode);
  };

  // ---- Stage A: spatial attention ----
  gemm(X0b, sa_wq_t, sa_bq, nullptr, Qb, DD, DD, 2);
  gemm(X0b, sa_wk_t, sa_bk, nullptr, Kb, DD, DD, 2);
  gemm(X0b, sa_wv_t, sa_bv, nullptr, Vb, DD, DD, 2);
  spatial_attn_mfma<<<dim3(B_ * T_, HH), 256, 0, stream>>>(Qb, Kb, Vb, MB, ATTb);
  gemm(ATTb, sa_wo_t, sa_bo, R3, nullptr, DD, DD, 0);
  add_ln<<<MTOK, 64, 0, stream>>>(x0, R3, sa_lw, sa_lb, R4, X1b);   // x1: R4 + X1b

  // ---- Stage B: temporal attention ----
  gemm(X1b, ta_wq_t, ta_bq, R0, nullptr, DD, DD, 0);
  gemm(X1b, ta_wk_t, ta_bk, R1, nullptr, DD, DD, 0);
  gemm(X1b, ta_wv_t, ta_bv, R2, nullptr, DD, DD, 0);
  {
    int total = B_ * NN * HH * T_;
    temporal_attn<<<(total + 255) / 256, 256, 0, stream>>>(R0, R1, R2, ATTb);
  }
  gemm(ATTb, ta_wo_t, ta_bo, R3, nullptr, DD, DD, 0);
  add_ln<<<MTOK, 64, 0, stream>>>(R4, R3, ta_lw, ta_lb, R0, X0b);   // x2: R0 + X0b

  // ---- Stage C: FFN ----
  gemm(X0b, f_w1_t, f_b1, nullptr, HIDb, FFD, DD, 1);               // GELU, bf16 hidden
  gemm(HIDb, f_w2_t, f_b2, R3, nullptr, DD, FFD, 0);
  add_ln<<<MTOK, 64, 0, stream>>>(R0, R3, f_lw, f_lb, out, nullptr);
}

// Round 6
// 414.745 us; speedup vs baseline: 3.6715x; 1.1267x over previous
//
#include <hip/hip_runtime.h>
#include <hip/hip_bf16.h>
#include <math.h>

#define B_   8
#define T_   12
#define NN   325
#define DD   256
#define HH   8
#define HD   32
#define FFD  1024
#define MTOK (B_*T_*NN)     // 31200 tokens
#define QKVD 768            // packed QKV row stride
#define ATT_SCALE 0.17677669529663687f   // 1/sqrt(32)
#define LN_EPS 1e-5f
#define NEG_BIG (-1e30f)

typedef __attribute__((ext_vector_type(8))) __bf16 bf16x8;
typedef __attribute__((ext_vector_type(4))) float  f32x4;
typedef __attribute__((ext_vector_type(4))) short  shortx4;
typedef __attribute__((ext_vector_type(8))) unsigned short ushortx8;

static __device__ inline float bf2f(unsigned short u) {
  union { float f; unsigned int i; } c; c.i = ((unsigned int)u) << 16; return c.f;
}

// 16x16x16 bf16 MFMA (ISA: v_mfma_f32_16x16x16_bf16; A/B = 4 bf16/lane)
#if __has_builtin(__builtin_amdgcn_mfma_f32_16x16x16bf16_1k)
#define MFMA16(a,b,c) __builtin_amdgcn_mfma_f32_16x16x16bf16_1k((a),(b),(c),0,0,0)
#else
static __device__ inline f32x4 mfma16_fn(shortx4 a, shortx4 b, f32x4 c) {
  f32x4 d;
  asm volatile("v_mfma_f32_16x16x16_bf16 %0, %1, %2, %3"
               : "=v"(d) : "v"(a), "v"(b), "v"(c));
  return d;
}
#define MFMA16(a,b,c) mfma16_fn((a),(b),(c))
#endif

// async global->LDS, 16B per lane, wave-uniform LDS base + lane*16
#define GLDS(gsrc, ldst) \
  __builtin_amdgcn_global_load_lds((const __attribute__((address_space(1))) void*)(gsrc), \
                                   (__attribute__((address_space(3))) void*)(ldst), 16, 0, 0)

// ---------------------------------------------------------------------------
// bf16 MFMA GEMM, min-2-phase double-buffered (T3-lite), N-fastest grid with
// bijective XCD swizzle (T1/m204). C[M,N] = A[M,K] @ Wt[N,K]^T + bias.
// 128x128 tile, BK=32, 4 waves. mode 0: fp32 out. 1: bf16+GELU. 2: bf16.
// ---------------------------------------------------------------------------
__global__ __launch_bounds__(256) void gemm_mfma(
    const __hip_bfloat16* __restrict__ A,
    const __hip_bfloat16* __restrict__ Wt,
    const float* __restrict__ bias,
    float* __restrict__ Cf, __hip_bfloat16* __restrict__ Cb,
    int Mr, int Nr, int Kr, int mode)
{
  __shared__ __hip_bfloat16 As[2][128 * 32];
  __shared__ __hip_bfloat16 Bs[2][128 * 32];

  // bijective XCD swizzle: each XCD gets a contiguous run of linear ids
  const int NB  = Nr >> 7;
  const int nwg = gridDim.x;
  {
  }
  const int orig = blockIdx.x;
  const int qq = nwg >> 3, rr = nwg & 7;
  const int xcd = orig & 7, off = orig >> 3;
  const int id = (xcd < rr ? xcd * (qq + 1) : rr * (qq + 1) + (xcd - rr) * qq) + off;
  const int n0 = (id % NB) * 128;   // N-block fastest: consecutive ids share A-panel
  const int m0 = (id / NB) * 128;

  const int tid  = threadIdx.x;
  const int w    = tid >> 6;
  const int lane = tid & 63;
  const int wr   = w >> 1, wc = w & 1;

  f32x4 acc[4][4] = {};

  const int srow = w * 32 + (lane >> 2);
  const int scol = (lane & 3) * 8;
  int ar0 = m0 + srow;      if (ar0 >= Mr) ar0 = Mr - 1;
  int ar1 = m0 + srow + 16; if (ar1 >= Mr) ar1 = Mr - 1;
  const size_t aOff0 = (size_t)ar0 * Kr + scol;
  const size_t aOff1 = (size_t)ar1 * Kr + scol;
  const size_t bOff0 = (size_t)(n0 + srow) * Kr + scol;
  const size_t bOff1 = (size_t)(n0 + srow + 16) * Kr + scol;

  const int lr = lane & 15;
  const int kb = (lane >> 4) * 8;
  const int nk = Kr >> 5;

#define STAGE_T(buf, k0) do { \
    GLDS(&A[aOff0 + (k0)],  &As[buf][(w * 32) * 32]); \
    GLDS(&A[aOff1 + (k0)],  &As[buf][(w * 32 + 16) * 32]); \
    GLDS(&Wt[bOff0 + (k0)], &Bs[buf][(w * 32) * 32]); \
    GLDS(&Wt[bOff1 + (k0)], &Bs[buf][(w * 32 + 16) * 32]); \
  } while (0)

#define COMPUTE_T(buf) do { \
    bf16x8 af[4], bfr[4]; \
    _Pragma("unroll") for (int i = 0; i < 4; ++i) { \
      af[i]  = *(const bf16x8*)&As[buf][(wr * 64 + i * 16 + lr) * 32 + kb]; \
      bfr[i] = *(const bf16x8*)&Bs[buf][(wc * 64 + i * 16 + lr) * 32 + kb]; \
    } \
    _Pragma("unroll") for (int i = 0; i < 4; ++i) \
      _Pragma("unroll") for (int j = 0; j < 4; ++j) \
        acc[i][j] = __builtin_amdgcn_mfma_f32_16x16x32_bf16(af[i], bfr[j], acc[i][j], 0, 0, 0); \
  } while (0)

  // prologue: tile 0 -> buf 0 (full drain: only non-overlapped stage)
  STAGE_T(0, 0);
  __syncthreads();
  int cur = 0;
  for (int k = 1; k < nk; ++k) {
    STAGE_T(cur ^ 1, k * 32);   // loads of tile k overlap compute of tile k-1
    COMPUTE_T(cur);
    __syncthreads();            // drains vmcnt (stage done) + all reads of cur done
    cur ^= 1;
  }
  COMPUTE_T(cur);
#undef STAGE_T
#undef COMPUTE_T

  // epilogue: C/D layout col = lane&15, row = (lane>>4)*4 + q
  const int rg = lane >> 4;
  #pragma unroll
  for (int i = 0; i < 4; ++i) {
    int rowb = m0 + wr * 64 + i * 16 + rg * 4;
    #pragma unroll
    for (int j = 0; j < 4; ++j) {
      int col = n0 + wc * 64 + j * 16 + lr;
      float bv = bias[col];
      #pragma unroll
      for (int q = 0; q < 4; ++q) {
        int gm = rowb + q;
        if (gm >= Mr) continue;
        float c = acc[i][j][q] + bv;
        if (mode == 0) {
          Cf[(size_t)gm * Nr + col] = c;
        } else {
          if (mode == 1) c = 0.5f * c * (1.f + erff(c * 0.70710678118654752f));
          Cb[(size_t)gm * Nr + col] = __float2bfloat16(c);
        }
      }
    }
  }
}

// ---------------------------------------------------------------------------
// Weight transpose + convert: Wt[N][K] bf16 <- W[K][N] fp32.
// ---------------------------------------------------------------------------
__global__ __launch_bounds__(256) void wt_cvt(
    const float* __restrict__ W, __hip_bfloat16* __restrict__ Wt, int K, int N)
{
  __shared__ float t[32][33];
  const int n0 = blockIdx.x * 32, k0 = blockIdx.y * 32;
  const int tx = threadIdx.x & 31, ty = threadIdx.x >> 5;
  #pragma unroll
  for (int i = 0; i < 32; i += 8)
    t[ty + i][tx] = W[(size_t)(k0 + ty + i) * N + n0 + tx];
  __syncthreads();
  #pragma unroll
  for (int i = 0; i < 32; i += 8)
    Wt[(size_t)(n0 + ty + i) * K + k0 + tx] = __float2bfloat16(t[tx][ty + i]);
}

__global__ __launch_bounds__(256) void cvt_bf16(
    const float* __restrict__ x, __hip_bfloat16* __restrict__ y, int n4)
{
  int i = blockIdx.x * 256 + threadIdx.x;
  if (i >= n4) return;
  float4 v = reinterpret_cast<const float4*>(x)[i];
  union { shortx4 s; __hip_bfloat16 h[4]; } u;
  u.h[0] = __float2bfloat16(v.x); u.h[1] = __float2bfloat16(v.y);
  u.h[2] = __float2bfloat16(v.z); u.h[3] = __float2bfloat16(v.w);
  reinterpret_cast<shortx4*>(y)[i] = u.s;
}

// concat 3x256 fp32 biases -> 768
__global__ __launch_bounds__(256) void bias_cat3(
    const float* __restrict__ a, const float* __restrict__ b,
    const float* __restrict__ c, float* __restrict__ o)
{
  int i = blockIdx.x * 256 + threadIdx.x;
  if (i < 256) o[i] = a[i];
  else if (i < 512) o[i] = b[i - 256];
  else if (i < 768) o[i] = c[i - 512];
}

// ---------------------------------------------------------------------------
// Pack adjacency mask to bits: mb[l][w] bit b = (adj[l][w*32+b] != 0).
// ---------------------------------------------------------------------------
__global__ __launch_bounds__(256) void maskpack(
    const int* __restrict__ adj, unsigned int* __restrict__ mb)
{
  int idx = blockIdx.x * 256 + threadIdx.x;
  if (idx >= NN * 11) return;
  int l = idx / 11, w = idx % 11;
  unsigned int bits = 0;
  #pragma unroll 4
  for (int b = 0; b < 32; ++b) {
    int m = w * 32 + b;
    if (m < NN && adj[l * NN + m] != 0) bits |= (1u << b);
  }
  mb[idx] = bits;
}

// ---------------------------------------------------------------------------
// MFMA spatial attention over packed QKV [M][768]. One WG per (g, h).
// S^T = mfma_16x16x32(K, Q); C-layout == x16 B-layout -> P feeds PV in-register.
// ---------------------------------------------------------------------------
__global__ __launch_bounds__(256) void spatial_attn_mfma(
    const __hip_bfloat16* __restrict__ qkv,
    const unsigned int* __restrict__ mb,
    __hip_bfloat16* __restrict__ out)
{
  constexpr int KP = 40;    // K_lds pitch: 80B rows, 2-way banks (free)
  constexpr int VP = 340;   // V^T pitch: 680B rows, 2-way (free)
  __shared__ unsigned short Kl[336 * KP];
  __shared__ unsigned short Vt[32 * VP];

  const int g = blockIdx.x, h = blockIdx.y;
  const int tid = threadIdx.x;
  const int w = tid >> 6, lane = tid & 63;
  const int lq = lane & 15, lg = lane >> 4;

  const size_t baseQ = (size_t)g * NN * QKVD + (size_t)h * HD;
  const size_t baseK = baseQ + 256;
  const size_t baseV = baseQ + 512;

  for (int idx = tid; idx < 32 * (VP - NN); idx += 256) {
    int d = idx / (VP - NN), kk = NN + idx % (VP - NN);
    Vt[d * VP + kk] = 0;
  }
  for (int idx = tid; idx < NN * 4; idx += 256) {
    int row = idx >> 2, cc = (idx & 3) * 8;
    union { bf16x8 v; unsigned short u[8]; } kv, vv;
    kv.v = *(const bf16x8*)&qkv[baseK + (size_t)row * QKVD + cc];
    *(bf16x8*)&Kl[row * KP + cc] = kv.v;
    vv.v = *(const bf16x8*)&qkv[baseV + (size_t)row * QKVD + cc];
    #pragma unroll
    for (int j = 0; j < 8; ++j) Vt[(cc + j) * VP + row] = vv.u[j];
  }
  __syncthreads();

  for (int qt = w; qt < 21; qt += 4) {
    const int query = qt * 16 + lq;
    const int qc = query < NN ? query : NN - 1;
    const bf16x8 qf = *(const bf16x8*)&qkv[baseQ + (size_t)qc * QKVD + lg * 8];
    const unsigned int* mrow = &mb[qc * 11];

    f32x4 accL = {0.f, 0.f, 0.f, 0.f};
    f32x4 accH = {0.f, 0.f, 0.f, 0.f};
    float mrun = -INFINITY, lrun = 0.f;

    for (int t = 0; t < 21; ++t) {
      bf16x8 kf = *(const bf16x8*)&Kl[(t * 16 + lq) * KP + lg * 8];
      f32x4 st = __builtin_amdgcn_mfma_f32_16x16x32_bf16(
          kf, qf, (f32x4){0.f, 0.f, 0.f, 0.f}, 0, 0, 0);
      const unsigned int mw = mrow[t >> 1];
      const int kbase = t * 16 + lg * 4;
      const int bbase = (t & 1) * 16 + lg * 4;
      float s[4];
      #pragma unroll
      for (int q = 0; q < 4; ++q) {
        float fill = (kbase + q < NN) ? NEG_BIG : -INFINITY;
        s[q] = ((mw >> (bbase + q)) & 1u) ? st[q] * ATT_SCALE : fill;
      }
      float tmax = fmaxf(fmaxf(s[0], s[1]), fmaxf(s[2], s[3]));
      tmax = fmaxf(tmax, __shfl_xor(tmax, 16));
      tmax = fmaxf(tmax, __shfl_xor(tmax, 32));
      const float mnew = fmaxf(mrun, tmax);
      const float corr = __expf(mrun - mnew);
      float p0 = __expf(s[0] - mnew), p1 = __expf(s[1] - mnew);
      float p2 = __expf(s[2] - mnew), p3 = __expf(s[3] - mnew);
      float ps = p0 + p1 + p2 + p3;
      ps += __shfl_xor(ps, 16);
      ps += __shfl_xor(ps, 32);
      lrun = lrun * corr + ps;
      mrun = mnew;
      accL *= corr; accH *= corr;
      union { shortx4 s4; __hip_bfloat16 hh[4]; } up;
      up.hh[0] = __float2bfloat16(p0); up.hh[1] = __float2bfloat16(p1);
      up.hh[2] = __float2bfloat16(p2); up.hh[3] = __float2bfloat16(p3);
      shortx4 vaL = *(const shortx4*)&Vt[lq * VP + kbase];
      shortx4 vaH = *(const shortx4*)&Vt[(lq + 16) * VP + kbase];
      accL = MFMA16(vaL, up.s4, accL);
      accH = MFMA16(vaH, up.s4, accH);
    }

    if (query < NN) {
      const float inv = 1.f / lrun;
      const size_t ob = ((size_t)(g * NN + query)) * DD + (size_t)h * HD;
      union { shortx4 s4; __hip_bfloat16 hh[4]; } uL, uH;
      #pragma unroll
      for (int q = 0; q < 4; ++q) {
        uL.hh[q] = __float2bfloat16(accL[q] * inv);
        uH.hh[q] = __float2bfloat16(accH[q] * inv);
      }
      *(shortx4*)&out[ob + lg * 4]      = uL.s4;
      *(shortx4*)&out[ob + 16 + lg * 4] = uH.s4;
    }
  }
}

// ---------------------------------------------------------------------------
// Temporal attention (causal, T=12) over packed bf16 QKV [M][768].
// ---------------------------------------------------------------------------
__global__ __launch_bounds__(256) void temporal_attn(
    const __hip_bfloat16* __restrict__ qkv, __hip_bfloat16* __restrict__ out)
{
  int idx = blockIdx.x * 256 + threadIdx.x;
  const int total = B_ * NN * HH * T_;
  if (idx >= total) return;

  int t  = idx % T_;
  int h  = (idx / T_) % HH;
  int n  = (idx / (T_ * HH)) % NN;
  int b  = idx / (T_ * HH * NN);

  const size_t tq = (size_t)((b * T_ + t) * NN + n) * QKVD + h * HD;
  float qr[HD];
  #pragma unroll
  for (int c8 = 0; c8 < 4; ++c8) {
    ushortx8 u = *(const ushortx8*)&qkv[tq + c8 * 8];
    #pragma unroll
    for (int j = 0; j < 8; ++j) qr[c8 * 8 + j] = bf2f(u[j]);
  }

  float o[HD] = {};
  float mrun = -INFINITY, lrun = 0.f;

  for (int tt = 0; tt <= t; ++tt) {
    const size_t tk = (size_t)((b * T_ + tt) * NN + n) * QKVD + h * HD;
    float s = 0.f;
    #pragma unroll
    for (int c8 = 0; c8 < 4; ++c8) {
      ushortx8 u = *(const ushortx8*)&qkv[tk + 256 + c8 * 8];
      #pragma unroll
      for (int j = 0; j < 8; ++j) s += qr[c8 * 8 + j] * bf2f(u[j]);
    }
    s *= ATT_SCALE;

    float mnew = fmaxf(mrun, s);
    float corr = __expf(mrun - mnew);
    float p = __expf(s - mnew);
    lrun = lrun * corr + p;
    #pragma unroll
    for (int c8 = 0; c8 < 4; ++c8) {
      ushortx8 u = *(const ushortx8*)&qkv[tk + 512 + c8 * 8];
      #pragma unroll
      for (int j = 0; j < 8; ++j) o[c8 * 8 + j] = o[c8 * 8 + j] * corr + p * bf2f(u[j]);
    }
    mrun = mnew;
  }

  float inv = 1.f / lrun;
  __hip_bfloat16* op = out + ((size_t)((b * T_ + t) * NN + n)) * DD + h * HD;
  #pragma unroll
  for (int d0 = 0; d0 < HD; d0 += 4) {
    union { shortx4 s; __hip_bfloat16 h4[4]; } u;
    #pragma unroll
    for (int j = 0; j < 4; ++j) u.h4[j] = __float2bfloat16(o[d0 + j] * inv);
    *reinterpret_cast<shortx4*>(op + d0) = u.s;
  }
}

// ---------------------------------------------------------------------------
// Fused residual-add + LayerNorm; fp32 out + optional bf16 copy. 1 wave/row.
// ---------------------------------------------------------------------------
__global__ __launch_bounds__(64) void add_ln(
    const float* __restrict__ x, const float* __restrict__ r,
    const float* __restrict__ w, const float* __restrict__ bb,
    float* __restrict__ y, __hip_bfloat16* __restrict__ ybf)
{
  const size_t row = blockIdx.x;
  const int lane = threadIdx.x;

  const float4 xv = reinterpret_cast<const float4*>(x + row * DD)[lane];
  const float4 rv = reinterpret_cast<const float4*>(r + row * DD)[lane];
  float e[4] = {xv.x + rv.x, xv.y + rv.y, xv.z + rv.z, xv.w + rv.w};

  float s  = e[0] + e[1] + e[2] + e[3];
  float ss = e[0]*e[0] + e[1]*e[1] + e[2]*e[2] + e[3]*e[3];
  #pragma unroll
  for (int off = 32; off > 0; off >>= 1) {
    s  += __shfl_xor(s,  off, 64);
    ss += __shfl_xor(ss, off, 64);
  }
  float mu  = s * (1.f / DD);
  float var = ss * (1.f / DD) - mu * mu;
  float rs  = rsqrtf(var + LN_EPS);

  const float4 wv = reinterpret_cast<const float4*>(w)[lane];
  const float4 bv = reinterpret_cast<const float4*>(bb)[lane];
  float o0 = (e[0] - mu) * rs * wv.x + bv.x;
  float o1 = (e[1] - mu) * rs * wv.y + bv.y;
  float o2 = (e[2] - mu) * rs * wv.z + bv.z;
  float o3 = (e[3] - mu) * rs * wv.w + bv.w;
  float4 yv = {o0, o1, o2, o3};
  reinterpret_cast<float4*>(y + row * DD)[lane] = yv;
  if (ybf) {
    union { shortx4 s4; __hip_bfloat16 h4[4]; } u;
    u.h4[0] = __float2bfloat16(o0); u.h4[1] = __float2bfloat16(o1);
    u.h4[2] = __float2bfloat16(o2); u.h4[3] = __float2bfloat16(o3);
    reinterpret_cast<shortx4*>(ybf + row * DD)[lane] = u.s4;
  }
}

// ---------------------------------------------------------------------------
extern "C" void kernel_launch(void* const* d_in, const int* in_sizes, int n_in,
                              void* d_out, int out_size, void* d_ws, size_t ws_size,
                              hipStream_t stream)
{
  const float* x0   = (const float*)d_in[0];
  const int*   adj  = (const int*)  d_in[1];
  const float* sa_wq = (const float*)d_in[2];
  const float* sa_bq = (const float*)d_in[3];
  const float* sa_wk = (const float*)d_in[4];
  const float* sa_bk = (const float*)d_in[5];
  const float* sa_wv = (const float*)d_in[6];
  const float* sa_bv = (const float*)d_in[7];
  const float* sa_wo = (const float*)d_in[8];
  const float* sa_bo = (const float*)d_in[9];
  const float* sa_lw = (const float*)d_in[10];
  const float* sa_lb = (const float*)d_in[11];
  const float* ta_wq = (const float*)d_in[12];
  const float* ta_bq = (const float*)d_in[13];
  const float* ta_wk = (const float*)d_in[14];
  const float* ta_bk = (const float*)d_in[15];
  const float* ta_wv = (const float*)d_in[16];
  const float* ta_bv = (const float*)d_in[17];
  const float* ta_wo = (const float*)d_in[18];
  const float* ta_bo = (const float*)d_in[19];
  const float* ta_lw = (const float*)d_in[20];
  const float* ta_lb = (const float*)d_in[21];
  const float* f_w1  = (const float*)d_in[22];
  const float* f_b1  = (const float*)d_in[23];
  const float* f_w2  = (const float*)d_in[24];
  const float* f_b2  = (const float*)d_in[25];
  const float* f_lw  = (const float*)d_in[26];
  const float* f_lb  = (const float*)d_in[27];

  float* out = (float*)d_out;
  float* ws  = (float*)d_ws;

  const size_t P = (size_t)MTOK * DD;           // 7,987,200 floats (32 MB)
  if (ws_size < 7 * P * sizeof(float)) return;

  float* R0 = ws;                                 // x2 fp32 [0,1P)
  __hip_bfloat16* QKVb = (__hip_bfloat16*)(ws + P);     // [M,768] bf16, [1P,2.5P)
  __hip_bfloat16* HIDb = (__hip_bfloat16*)(ws + P);     // [M,1024] bf16, stage C [1P,3P)
  float* R3 = ws + 3 * P;                         // proj out fp32 [3P,4P)
  float* R4 = ws + 4 * P;                         // x1 fp32 [4P,5P)
  __hip_bfloat16* X0b  = (__hip_bfloat16*)(ws + 5 * P);          // [5P,5.5P)
  __hip_bfloat16* X1b  = (__hip_bfloat16*)(ws + 5 * P + P / 2);  // [5.5P,6P)
  __hip_bfloat16* ATTb = (__hip_bfloat16*)(ws + 6 * P);          // [6P,6.5P)
  __hip_bfloat16* Wb   = (__hip_bfloat16*)(ws + 6 * P + P / 2);  // weights

  __hip_bfloat16* sa_qkv_t = Wb;                 // [768][256]
  __hip_bfloat16* ta_qkv_t = Wb + 196608;        // [768][256]
  __hip_bfloat16* sa_wo_t  = Wb + 393216;        // [256][256]
  __hip_bfloat16* ta_wo_t  = Wb + 458752;
  __hip_bfloat16* f_w1_t   = Wb + 524288;        // [1024][256]
  __hip_bfloat16* f_w2_t   = Wb + 786432;        // [256][1024]
  float* sa_qkvb = (float*)(Wb + 1048576);       // [768]
  float* ta_qkvb = sa_qkvb + 768;                // [768]
  unsigned int* MB = (unsigned int*)(ta_qkvb + 768);   // 325*11

  // ---- prep ----
  wt_cvt<<<dim3(DD/32, DD/32), 256, 0, stream>>>(sa_wq, sa_qkv_t,          DD, DD);
  wt_cvt<<<dim3(DD/32, DD/32), 256, 0, stream>>>(sa_wk, sa_qkv_t + 65536,  DD, DD);
  wt_cvt<<<dim3(DD/32, DD/32), 256, 0, stream>>>(sa_wv, sa_qkv_t + 131072, DD, DD);
  wt_cvt<<<dim3(DD/32, DD/32), 256, 0, stream>>>(ta_wq, ta_qkv_t,          DD, DD);
  wt_cvt<<<dim3(DD/32, DD/32), 256, 0, stream>>>(ta_wk, ta_qkv_t + 65536,  DD, DD);
  wt_cvt<<<dim3(DD/32, DD/32), 256, 0, stream>>>(ta_wv, ta_qkv_t + 131072, DD, DD);
  wt_cvt<<<dim3(DD/32, DD/32), 256, 0, stream>>>(sa_wo, sa_wo_t, DD, DD);
  wt_cvt<<<dim3(DD/32, DD/32), 256, 0, stream>>>(ta_wo, ta_wo_t, DD, DD);
  wt_cvt<<<dim3(FFD/32, DD/32), 256, 0, stream>>>(f_w1, f_w1_t, DD, FFD);
  wt_cvt<<<dim3(DD/32, FFD/32), 256, 0, stream>>>(f_w2, f_w2_t, FFD, DD);
  bias_cat3<<<3, 256, 0, stream>>>(sa_bq, sa_bk, sa_bv, sa_qkvb);
  bias_cat3<<<3, 256, 0, stream>>>(ta_bq, ta_bk, ta_bv, ta_qkvb);
  maskpack<<<(NN * 11 + 255) / 256, 256, 0, stream>>>(adj, MB);
  {
    int n4 = (int)(P / 4);
    cvt_bf16<<<(n4 + 255) / 256, 256, 0, stream>>>(x0, X0b, n4);
  }

  const int MBk = (MTOK + 127) / 128;   // 244
  auto gemm = [&](const __hip_bfloat16* A, const __hip_bfloat16* Wt, const float* bias,
                  float* Cf, __hip_bfloat16* Cb, int Nr, int Kr, int mode) {
    int nwg = (Nr / 128) * MBk;
    gemm_mfma<<<nwg, 256, 0, stream>>>(A, Wt, bias, Cf, Cb, MTOK, Nr, Kr, mode);
  };

  // ---- Stage A: spatial attention ----
  gemm(X0b, sa_qkv_t, sa_qkvb, nullptr, QKVb, QKVD, DD, 2);
  spatial_attn_mfma<<<dim3(B_ * T_, HH), 256, 0, stream>>>(QKVb, MB, ATTb);
  gemm(ATTb, sa_wo_t, sa_bo, R3, nullptr, DD, DD, 0);
  add_ln<<<MTOK, 64, 0, stream>>>(x0, R3, sa_lw, sa_lb, R4, X1b);   // x1: R4 + X1b

  // ---- Stage B: temporal attention ----
  gemm(X1b, ta_qkv_t, ta_qkvb, nullptr, QKVb, QKVD, DD, 2);
  {
    int total = B_ * NN * HH * T_;
    temporal_attn<<<(total + 255) / 256, 256, 0, stream>>>(QKVb, ATTb);
  }
  gemm(ATTb, ta_wo_t, ta_bo, R3, nullptr, DD, DD, 0);
  add_ln<<<MTOK, 64, 0, stream>>>(R4, R3, ta_lw, ta_lb, R0, X0b);   // x2: R0 + X0b

  // ---- Stage C: FFN ----
  gemm(X0b, f_w1_t, f_b1, nullptr, HIDb, FFD, DD, 1);               // GELU, bf16 hidden
  gemm(HIDb, f_w2_t, f_b2, R3, nullptr, DD, FFD, 0);
  add_ln<<<MTOK, 64, 0, stream>>>(R0, R3, f_lw, f_lb, out, nullptr);
}

// Round 7
// 413.184 us; speedup vs baseline: 3.6853x; 1.0038x over previous
//
#include <hip/hip_runtime.h>
#include <hip/hip_bf16.h>
#include <math.h>

#define B_   8
#define T_   12
#define NN   325
#define DD   256
#define HH   8
#define HD   32
#define FFD  1024
#define MTOK (B_*T_*NN)     // 31200 tokens
#define QKVD 768            // packed QKV row stride
#define ATT_SCALE 0.17677669529663687f   // 1/sqrt(32)
#define LN_EPS 1e-5f
#define NEG_BIG (-1e30f)

typedef __attribute__((ext_vector_type(8))) __bf16 bf16x8;
typedef __attribute__((ext_vector_type(4))) float  f32x4;
typedef __attribute__((ext_vector_type(4))) short  shortx4;
typedef __attribute__((ext_vector_type(8))) unsigned short ushortx8;

static __device__ inline float bf2f(unsigned short u) {
  union { float f; unsigned int i; } c; c.i = ((unsigned int)u) << 16; return c.f;
}

// 16x16x16 bf16 MFMA (ISA: v_mfma_f32_16x16x16_bf16; A/B = 4 bf16/lane)
#if __has_builtin(__builtin_amdgcn_mfma_f32_16x16x16bf16_1k)
#define MFMA16(a,b,c) __builtin_amdgcn_mfma_f32_16x16x16bf16_1k((a),(b),(c),0,0,0)
#else
static __device__ inline f32x4 mfma16_fn(shortx4 a, shortx4 b, f32x4 c) {
  f32x4 d;
  asm volatile("v_mfma_f32_16x16x16_bf16 %0, %1, %2, %3"
               : "=v"(d) : "v"(a), "v"(b), "v"(c));
  return d;
}
#define MFMA16(a,b,c) mfma16_fn((a),(b),(c))
#endif

// async global->LDS, 16B per lane, wave-uniform LDS base + lane*16
#define GLDS(gsrc, ldst) \
  __builtin_amdgcn_global_load_lds((const __attribute__((address_space(1))) void*)(gsrc), \
                                   (__attribute__((address_space(3))) void*)(ldst), 16, 0, 0)

// ---------------------------------------------------------------------------
// bf16 MFMA GEMM: counted-vmcnt 2-deep pipeline (T4) + both-sides LDS swizzle
// (T2, rule 21: pre-swizzled global source, linear LDS dest, swizzled read).
// N-fastest grid + bijective XCD swizzle (T1). C[M,N] = A[M,K]@Wt[N,K]^T + bias.
// 128x128 tile, BK=32, 4 waves. mode 0: fp32 out. 1: bf16+GELU. 2: bf16.
// ---------------------------------------------------------------------------
__global__ __launch_bounds__(256) void gemm_mfma(
    const __hip_bfloat16* __restrict__ A,
    const __hip_bfloat16* __restrict__ Wt,
    const float* __restrict__ bias,
    float* __restrict__ Cf, __hip_bfloat16* __restrict__ Cb,
    int Mr, int Nr, int Kr, int mode)
{
  __shared__ __hip_bfloat16 As[2][128 * 32];
  __shared__ __hip_bfloat16 Bs[2][128 * 32];

  // bijective XCD swizzle: each XCD gets a contiguous run of linear ids
  const int NB  = Nr >> 7;
  const int nwg = gridDim.x;
  const int orig = blockIdx.x;
  const int qq = nwg >> 3, rr = nwg & 7;
  const int xcd = orig & 7, off = orig >> 3;
  const int id = (xcd < rr ? xcd * (qq + 1) : rr * (qq + 1) + (xcd - rr) * qq) + off;
  const int n0 = (id % NB) * 128;   // N fastest: consecutive ids share A-panel
  const int m0 = (id / NB) * 128;

  const int tid  = threadIdx.x;
  const int w    = tid >> 6;
  const int lane = tid & 63;
  const int wr   = w >> 1, wc = w & 1;

  f32x4 acc[4][4] = {};

  // ---- staging addressing (source pre-swizzle, rule 21) ----
  const int c4   = lane & 3;                 // 16B unit within 64B row
  const int r0   = w * 32 + (lane >> 2);     // LDS row (chunk0; chunk1=+16, same swz)
  const int csw  = (c4 - (r0 >> 1)) & 3;     // swizzled source 16B-unit
  const int scol = csw * 8;                  // bf16 col offset
  int ar0 = m0 + r0;      if (ar0 >= Mr) ar0 = Mr - 1;
  int ar1 = m0 + r0 + 16; if (ar1 >= Mr) ar1 = Mr - 1;
  const size_t aOff0 = (size_t)ar0 * Kr + scol;
  const size_t aOff1 = (size_t)ar1 * Kr + scol;
  const size_t bOff0 = (size_t)(n0 + r0) * Kr + scol;
  const size_t bOff1 = (size_t)(n0 + r0 + 16) * Kr + scol;

  // ---- fragment read addressing (swizzled; content = row's k-chunk lg*8) ----
  const int lr = lane & 15;
  const int lg = lane >> 4;
  int offA[4], offB[4];
  #pragma unroll
  for (int i = 0; i < 4; ++i) {
    int rA = wr * 64 + i * 16 + lr;
    offA[i] = rA * 32 + (((lg + (rA >> 1)) & 3) * 8);
    int rB = wc * 64 + i * 16 + lr;
    offB[i] = rB * 32 + (((lg + (rB >> 1)) & 3) * 8);
  }
  const int nk = Kr >> 5;

#define STAGE_T(buf, k0) do { \
    GLDS(&A[aOff0 + (k0)],  &As[buf][(w * 32) * 32]); \
    GLDS(&A[aOff1 + (k0)],  &As[buf][(w * 32 + 16) * 32]); \
    GLDS(&Wt[bOff0 + (k0)], &Bs[buf][(w * 32) * 32]); \
    GLDS(&Wt[bOff1 + (k0)], &Bs[buf][(w * 32 + 16) * 32]); \
  } while (0)

  // prologue: 2 tiles in flight
  STAGE_T(0, 0);
  if (nk > 1) STAGE_T(1, 32);

  for (int k = 0; k < nk; ++k) {
    // own tile-k loads done (4 newest = tile k+1 stay in flight)
    if (k + 1 < nk) asm volatile("s_waitcnt vmcnt(4)" ::: "memory");
    else            asm volatile("s_waitcnt vmcnt(0)" ::: "memory");
    __builtin_amdgcn_s_barrier();            // all waves' tile-k loads landed

    const int buf = k & 1;
    bf16x8 af[4], bfr[4];
    #pragma unroll
    for (int i = 0; i < 4; ++i) {
      af[i]  = *(const bf16x8*)&As[buf][offA[i]];
      bfr[i] = *(const bf16x8*)&Bs[buf][offB[i]];
    }
    asm volatile("s_waitcnt lgkmcnt(0)" ::: "memory");
    __builtin_amdgcn_sched_barrier(0);       // rule 18: pin reads before barrier
    __builtin_amdgcn_s_barrier();            // all waves done reading buf

    if (k + 2 < nk) STAGE_T(buf, (k + 2) * 32);  // overwrite freed buffer

    #pragma unroll
    for (int i = 0; i < 4; ++i)
      #pragma unroll
      for (int j = 0; j < 4; ++j)
        acc[i][j] = __builtin_amdgcn_mfma_f32_16x16x32_bf16(af[i], bfr[j], acc[i][j], 0, 0, 0);
  }
#undef STAGE_T

  // epilogue: C/D layout col = lane&15, row = (lane>>4)*4 + q
  const int rg = lg;
  #pragma unroll
  for (int i = 0; i < 4; ++i) {
    int rowb = m0 + wr * 64 + i * 16 + rg * 4;
    #pragma unroll
    for (int j = 0; j < 4; ++j) {
      int col = n0 + wc * 64 + j * 16 + lr;
      float bv = bias[col];
      #pragma unroll
      for (int q = 0; q < 4; ++q) {
        int gm = rowb + q;
        if (gm >= Mr) continue;
        float c = acc[i][j][q] + bv;
        if (mode == 0) {
          Cf[(size_t)gm * Nr + col] = c;
        } else {
          if (mode == 1) c = 0.5f * c * (1.f + erff(c * 0.70710678118654752f));
          Cb[(size_t)gm * Nr + col] = __float2bfloat16(c);
        }
      }
    }
  }
}

// ---------------------------------------------------------------------------
// Weight transpose + convert: Wt[N][K] bf16 <- W[K][N] fp32.
// ---------------------------------------------------------------------------
__global__ __launch_bounds__(256) void wt_cvt(
    const float* __restrict__ W, __hip_bfloat16* __restrict__ Wt, int K, int N)
{
  __shared__ float t[32][33];
  const int n0 = blockIdx.x * 32, k0 = blockIdx.y * 32;
  const int tx = threadIdx.x & 31, ty = threadIdx.x >> 5;
  #pragma unroll
  for (int i = 0; i < 32; i += 8)
    t[ty + i][tx] = W[(size_t)(k0 + ty + i) * N + n0 + tx];
  __syncthreads();
  #pragma unroll
  for (int i = 0; i < 32; i += 8)
    Wt[(size_t)(n0 + ty + i) * K + k0 + tx] = __float2bfloat16(t[tx][ty + i]);
}

__global__ __launch_bounds__(256) void cvt_bf16(
    const float* __restrict__ x, __hip_bfloat16* __restrict__ y, int n4)
{
  int i = blockIdx.x * 256 + threadIdx.x;
  if (i >= n4) return;
  float4 v = reinterpret_cast<const float4*>(x)[i];
  union { shortx4 s; __hip_bfloat16 h[4]; } u;
  u.h[0] = __float2bfloat16(v.x); u.h[1] = __float2bfloat16(v.y);
  u.h[2] = __float2bfloat16(v.z); u.h[3] = __float2bfloat16(v.w);
  reinterpret_cast<shortx4*>(y)[i] = u.s;
}

// concat 3x256 fp32 biases -> 768
__global__ __launch_bounds__(256) void bias_cat3(
    const float* __restrict__ a, const float* __restrict__ b,
    const float* __restrict__ c, float* __restrict__ o)
{
  int i = blockIdx.x * 256 + threadIdx.x;
  if (i < 256) o[i] = a[i];
  else if (i < 512) o[i] = b[i - 256];
  else if (i < 768) o[i] = c[i - 512];
}

// ---------------------------------------------------------------------------
// Pack adjacency mask to bits: mb[l][w] bit b = (adj[l][w*32+b] != 0).
// ---------------------------------------------------------------------------
__global__ __launch_bounds__(256) void maskpack(
    const int* __restrict__ adj, unsigned int* __restrict__ mb)
{
  int idx = blockIdx.x * 256 + threadIdx.x;
  if (idx >= NN * 11) return;
  int l = idx / 11, w = idx % 11;
  unsigned int bits = 0;
  #pragma unroll 4
  for (int b = 0; b < 32; ++b) {
    int m = w * 32 + b;
    if (m < NN && adj[l * NN + m] != 0) bits |= (1u << b);
  }
  mb[idx] = bits;
}

// ---------------------------------------------------------------------------
// MFMA spatial attention over packed QKV [M][768]. One WG per (g, h).
// S^T = mfma_16x16x32(K, Q); C-layout == x16 B-layout -> P feeds PV in-register.
// ---------------------------------------------------------------------------
__global__ __launch_bounds__(256) void spatial_attn_mfma(
    const __hip_bfloat16* __restrict__ qkv,
    const unsigned int* __restrict__ mb,
    __hip_bfloat16* __restrict__ out)
{
  constexpr int KP = 40;    // K_lds pitch: 80B rows, 2-way banks (free)
  constexpr int VP = 340;   // V^T pitch: 680B rows, 2-way (free)
  __shared__ unsigned short Kl[336 * KP];
  __shared__ unsigned short Vt[32 * VP];

  const int g = blockIdx.x, h = blockIdx.y;
  const int tid = threadIdx.x;
  const int w = tid >> 6, lane = tid & 63;
  const int lq = lane & 15, lg = lane >> 4;

  const size_t baseQ = (size_t)g * NN * QKVD + (size_t)h * HD;
  const size_t baseK = baseQ + 256;
  const size_t baseV = baseQ + 512;

  for (int idx = tid; idx < 32 * (VP - NN); idx += 256) {
    int d = idx / (VP - NN), kk = NN + idx % (VP - NN);
    Vt[d * VP + kk] = 0;
  }
  for (int idx = tid; idx < NN * 4; idx += 256) {
    int row = idx >> 2, cc = (idx & 3) * 8;
    union { bf16x8 v; unsigned short u[8]; } kv, vv;
    kv.v = *(const bf16x8*)&qkv[baseK + (size_t)row * QKVD + cc];
    *(bf16x8*)&Kl[row * KP + cc] = kv.v;
    vv.v = *(const bf16x8*)&qkv[baseV + (size_t)row * QKVD + cc];
    #pragma unroll
    for (int j = 0; j < 8; ++j) Vt[(cc + j) * VP + row] = vv.u[j];
  }
  __syncthreads();

  for (int qt = w; qt < 21; qt += 4) {
    const int query = qt * 16 + lq;
    const int qc = query < NN ? query : NN - 1;
    const bf16x8 qf = *(const bf16x8*)&qkv[baseQ + (size_t)qc * QKVD + lg * 8];
    const unsigned int* mrow = &mb[qc * 11];

    f32x4 accL = {0.f, 0.f, 0.f, 0.f};
    f32x4 accH = {0.f, 0.f, 0.f, 0.f};
    float mrun = -INFINITY, lrun = 0.f;

    for (int t = 0; t < 21; ++t) {
      bf16x8 kf = *(const bf16x8*)&Kl[(t * 16 + lq) * KP + lg * 8];
      f32x4 st = __builtin_amdgcn_mfma_f32_16x16x32_bf16(
          kf, qf, (f32x4){0.f, 0.f, 0.f, 0.f}, 0, 0, 0);
      const unsigned int mw = mrow[t >> 1];
      const int kbase = t * 16 + lg * 4;
      const int bbase = (t & 1) * 16 + lg * 4;
      float s[4];
      #pragma unroll
      for (int q = 0; q < 4; ++q) {
        float fill = (kbase + q < NN) ? NEG_BIG : -INFINITY;
        s[q] = ((mw >> (bbase + q)) & 1u) ? st[q] * ATT_SCALE : fill;
      }
      float tmax = fmaxf(fmaxf(s[0], s[1]), fmaxf(s[2], s[3]));
      tmax = fmaxf(tmax, __shfl_xor(tmax, 16));
      tmax = fmaxf(tmax, __shfl_xor(tmax, 32));
      const float mnew = fmaxf(mrun, tmax);
      const float corr = __expf(mrun - mnew);
      float p0 = __expf(s[0] - mnew), p1 = __expf(s[1] - mnew);
      float p2 = __expf(s[2] - mnew), p3 = __expf(s[3] - mnew);
      float ps = p0 + p1 + p2 + p3;
      ps += __shfl_xor(ps, 16);
      ps += __shfl_xor(ps, 32);
      lrun = lrun * corr + ps;
      mrun = mnew;
      accL *= corr; accH *= corr;
      union { shortx4 s4; __hip_bfloat16 hh[4]; } up;
      up.hh[0] = __float2bfloat16(p0); up.hh[1] = __float2bfloat16(p1);
      up.hh[2] = __float2bfloat16(p2); up.hh[3] = __float2bfloat16(p3);
      shortx4 vaL = *(const shortx4*)&Vt[lq * VP + kbase];
      shortx4 vaH = *(const shortx4*)&Vt[(lq + 16) * VP + kbase];
      accL = MFMA16(vaL, up.s4, accL);
      accH = MFMA16(vaH, up.s4, accH);
    }

    if (query < NN) {
      const float inv = 1.f / lrun;
      const size_t ob = ((size_t)(g * NN + query)) * DD + (size_t)h * HD;
      union { shortx4 s4; __hip_bfloat16 hh[4]; } uL, uH;
      #pragma unroll
      for (int q = 0; q < 4; ++q) {
        uL.hh[q] = __float2bfloat16(accL[q] * inv);
        uH.hh[q] = __float2bfloat16(accH[q] * inv);
      }
      *(shortx4*)&out[ob + lg * 4]      = uL.s4;
      *(shortx4*)&out[ob + 16 + lg * 4] = uH.s4;
    }
  }
}

// ---------------------------------------------------------------------------
// Temporal attention (causal, T=12) over packed bf16 QKV [M][768].
// ---------------------------------------------------------------------------
__global__ __launch_bounds__(256) void temporal_attn(
    const __hip_bfloat16* __restrict__ qkv, __hip_bfloat16* __restrict__ out)
{
  int idx = blockIdx.x * 256 + threadIdx.x;
  const int total = B_ * NN * HH * T_;
  if (idx >= total) return;

  int t  = idx % T_;
  int h  = (idx / T_) % HH;
  int n  = (idx / (T_ * HH)) % NN;
  int b  = idx / (T_ * HH * NN);

  const size_t tq = (size_t)((b * T_ + t) * NN + n) * QKVD + h * HD;
  float qr[HD];
  #pragma unroll
  for (int c8 = 0; c8 < 4; ++c8) {
    ushortx8 u = *(const ushortx8*)&qkv[tq + c8 * 8];
    #pragma unroll
    for (int j = 0; j < 8; ++j) qr[c8 * 8 + j] = bf2f(u[j]);
  }

  float o[HD] = {};
  float mrun = -INFINITY, lrun = 0.f;

  for (int tt = 0; tt <= t; ++tt) {
    const size_t tk = (size_t)((b * T_ + tt) * NN + n) * QKVD + h * HD;
    float s = 0.f;
    #pragma unroll
    for (int c8 = 0; c8 < 4; ++c8) {
      ushortx8 u = *(const ushortx8*)&qkv[tk + 256 + c8 * 8];
      #pragma unroll
      for (int j = 0; j < 8; ++j) s += qr[c8 * 8 + j] * bf2f(u[j]);
    }
    s *= ATT_SCALE;

    float mnew = fmaxf(mrun, s);
    float corr = __expf(mrun - mnew);
    float p = __expf(s - mnew);
    lrun = lrun * corr + p;
    #pragma unroll
    for (int c8 = 0; c8 < 4; ++c8) {
      ushortx8 u = *(const ushortx8*)&qkv[tk + 512 + c8 * 8];
      #pragma unroll
      for (int j = 0; j < 8; ++j) o[c8 * 8 + j] = o[c8 * 8 + j] * corr + p * bf2f(u[j]);
    }
    mrun = mnew;
  }

  float inv = 1.f / lrun;
  __hip_bfloat16* op = out + ((size_t)((b * T_ + t) * NN + n)) * DD + h * HD;
  #pragma unroll
  for (int d0 = 0; d0 < HD; d0 += 4) {
    union { shortx4 s; __hip_bfloat16 h4[4]; } u;
    #pragma unroll
    for (int j = 0; j < 4; ++j) u.h4[j] = __float2bfloat16(o[d0 + j] * inv);
    *reinterpret_cast<shortx4*>(op + d0) = u.s;
  }
}

// ---------------------------------------------------------------------------
// Fused residual-add + LayerNorm; fp32 out + optional bf16 copy. 1 wave/row.
// ---------------------------------------------------------------------------
__global__ __launch_bounds__(64) void add_ln(
    const float* __restrict__ x, const float* __restrict__ r,
    const float* __restrict__ w, const float* __restrict__ bb,
    float* __restrict__ y, __hip_bfloat16* __restrict__ ybf)
{
  const size_t row = blockIdx.x;
  const int lane = threadIdx.x;

  const float4 xv = reinterpret_cast<const float4*>(x + row * DD)[lane];
  const float4 rv = reinterpret_cast<const float4*>(r + row * DD)[lane];
  float e[4] = {xv.x + rv.x, xv.y + rv.y, xv.z + rv.z, xv.w + rv.w};

  float s  = e[0] + e[1] + e[2] + e[3];
  float ss = e[0]*e[0] + e[1]*e[1] + e[2]*e[2] + e[3]*e[3];
  #pragma unroll
  for (int off = 32; off > 0; off >>= 1) {
    s  += __shfl_xor(s,  off, 64);
    ss += __shfl_xor(ss, off, 64);
  }
  float mu  = s * (1.f / DD);
  float var = ss * (1.f / DD) - mu * mu;
  float rs  = rsqrtf(var + LN_EPS);

  const float4 wv = reinterpret_cast<const float4*>(w)[lane];
  const float4 bv = reinterpret_cast<const float4*>(bb)[lane];
  float o0 = (e[0] - mu) * rs * wv.x + bv.x;
  float o1 = (e[1] - mu) * rs * wv.y + bv.y;
  float o2 = (e[2] - mu) * rs * wv.z + bv.z;
  float o3 = (e[3] - mu) * rs * wv.w + bv.w;
  float4 yv = {o0, o1, o2, o3};
  reinterpret_cast<float4*>(y + row * DD)[lane] = yv;
  if (ybf) {
    union { shortx4 s4; __hip_bfloat16 h4[4]; } u;
    u.h4[0] = __float2bfloat16(o0); u.h4[1] = __float2bfloat16(o1);
    u.h4[2] = __float2bfloat16(o2); u.h4[3] = __float2bfloat16(o3);
    reinterpret_cast<shortx4*>(ybf + row * DD)[lane] = u.s4;
  }
}

// ---------------------------------------------------------------------------
extern "C" void kernel_launch(void* const* d_in, const int* in_sizes, int n_in,
                              void* d_out, int out_size, void* d_ws, size_t ws_size,
                              hipStream_t stream)
{
  const float* x0   = (const float*)d_in[0];
  const int*   adj  = (const int*)  d_in[1];
  const float* sa_wq = (const float*)d_in[2];
  const float* sa_bq = (const float*)d_in[3];
  const float* sa_wk = (const float*)d_in[4];
  const float* sa_bk = (const float*)d_in[5];
  const float* sa_wv = (const float*)d_in[6];
  const float* sa_bv = (const float*)d_in[7];
  const float* sa_wo = (const float*)d_in[8];
  const float* sa_bo = (const float*)d_in[9];
  const float* sa_lw = (const float*)d_in[10];
  const float* sa_lb = (const float*)d_in[11];
  const float* ta_wq = (const float*)d_in[12];
  const float* ta_bq = (const float*)d_in[13];
  const float* ta_wk = (const float*)d_in[14];
  const float* ta_bk = (const float*)d_in[15];
  const float* ta_wv = (const float*)d_in[16];
  const float* ta_bv = (const float*)d_in[17];
  const float* ta_wo = (const float*)d_in[18];
  const float* ta_bo = (const float*)d_in[19];
  const float* ta_lw = (const float*)d_in[20];
  const float* ta_lb = (const float*)d_in[21];
  const float* f_w1  = (const float*)d_in[22];
  const float* f_b1  = (const float*)d_in[23];
  const float* f_w2  = (const float*)d_in[24];
  const float* f_b2  = (const float*)d_in[25];
  const float* f_lw  = (const float*)d_in[26];
  const float* f_lb  = (const float*)d_in[27];

  float* out = (float*)d_out;
  float* ws  = (float*)d_ws;

  const size_t P = (size_t)MTOK * DD;           // 7,987,200 floats (32 MB)
  if (ws_size < 7 * P * sizeof(float)) return;

  float* R0 = ws;                                 // x2 fp32 [0,1P)
  __hip_bfloat16* QKVb = (__hip_bfloat16*)(ws + P);     // [M,768] bf16, [1P,2.5P)
  __hip_bfloat16* HIDb = (__hip_bfloat16*)(ws + P);     // [M,1024] bf16, stage C [1P,3P)
  float* R3 = ws + 3 * P;                         // proj out fp32 [3P,4P)
  float* R4 = ws + 4 * P;                         // x1 fp32 [4P,5P)
  __hip_bfloat16* X0b  = (__hip_bfloat16*)(ws + 5 * P);          // [5P,5.5P)
  __hip_bfloat16* X1b  = (__hip_bfloat16*)(ws + 5 * P + P / 2);  // [5.5P,6P)
  __hip_bfloat16* ATTb = (__hip_bfloat16*)(ws + 6 * P);          // [6P,6.5P)
  __hip_bfloat16* Wb   = (__hip_bfloat16*)(ws + 6 * P + P / 2);  // weights

  __hip_bfloat16* sa_qkv_t = Wb;                 // [768][256]
  __hip_bfloat16* ta_qkv_t = Wb + 196608;        // [768][256]
  __hip_bfloat16* sa_wo_t  = Wb + 393216;        // [256][256]
  __hip_bfloat16* ta_wo_t  = Wb + 458752;
  __hip_bfloat16* f_w1_t   = Wb + 524288;        // [1024][256]
  __hip_bfloat16* f_w2_t   = Wb + 786432;        // [256][1024]
  float* sa_qkvb = (float*)(Wb + 1048576);       // [768]
  float* ta_qkvb = sa_qkvb + 768;                // [768]
  unsigned int* MB = (unsigned int*)(ta_qkvb + 768);   // 325*11

  // ---- prep ----
  wt_cvt<<<dim3(DD/32, DD/32), 256, 0, stream>>>(sa_wq, sa_qkv_t,          DD, DD);
  wt_cvt<<<dim3(DD/32, DD/32), 256, 0, stream>>>(sa_wk, sa_qkv_t + 65536,  DD, DD);
  wt_cvt<<<dim3(DD/32, DD/32), 256, 0, stream>>>(sa_wv, sa_qkv_t + 131072, DD, DD);
  wt_cvt<<<dim3(DD/32, DD/32), 256, 0, stream>>>(ta_wq, ta_qkv_t,          DD, DD);
  wt_cvt<<<dim3(DD/32, DD/32), 256, 0, stream>>>(ta_wk, ta_qkv_t + 65536,  DD, DD);
  wt_cvt<<<dim3(DD/32, DD/32), 256, 0, stream>>>(ta_wv, ta_qkv_t + 131072, DD, DD);
  wt_cvt<<<dim3(DD/32, DD/32), 256, 0, stream>>>(sa_wo, sa_wo_t, DD, DD);
  wt_cvt<<<dim3(DD/32, DD/32), 256, 0, stream>>>(ta_wo, ta_wo_t, DD, DD);
  wt_cvt<<<dim3(FFD/32, DD/32), 256, 0, stream>>>(f_w1, f_w1_t, DD, FFD);
  wt_cvt<<<dim3(DD/32, FFD/32), 256, 0, stream>>>(f_w2, f_w2_t, FFD, DD);
  bias_cat3<<<3, 256, 0, stream>>>(sa_bq, sa_bk, sa_bv, sa_qkvb);
  bias_cat3<<<3, 256, 0, stream>>>(ta_bq, ta_bk, ta_bv, ta_qkvb);
  maskpack<<<(NN * 11 + 255) / 256, 256, 0, stream>>>(adj, MB);
  {
    int n4 = (int)(P / 4);
    cvt_bf16<<<(n4 + 255) / 256, 256, 0, stream>>>(x0, X0b, n4);
  }

  const int MBk = (MTOK + 127) / 128;   // 244
  auto gemm = [&](const __hip_bfloat16* A, const __hip_bfloat16* Wt, const float* bias,
                  float* Cf, __hip_bfloat16* Cb, int Nr, int Kr, int mode) {
    int nwg = (Nr / 128) * MBk;
    gemm_mfma<<<nwg, 256, 0, stream>>>(A, Wt, bias, Cf, Cb, MTOK, Nr, Kr, mode);
  };

  // ---- Stage A: spatial attention ----
  gemm(X0b, sa_qkv_t, sa_qkvb, nullptr, QKVb, QKVD, DD, 2);
  spatial_attn_mfma<<<dim3(B_ * T_, HH), 256, 0, stream>>>(QKVb, MB, ATTb);
  gemm(ATTb, sa_wo_t, sa_bo, R3, nullptr, DD, DD, 0);
  add_ln<<<MTOK, 64, 0, stream>>>(x0, R3, sa_lw, sa_lb, R4, X1b);   // x1: R4 + X1b

  // ---- Stage B: temporal attention ----
  gemm(X1b, ta_qkv_t, ta_qkvb, nullptr, QKVb, QKVD, DD, 2);
  {
    int total = B_ * NN * HH * T_;
    temporal_attn<<<(total + 255) / 256, 256, 0, stream>>>(QKVb, ATTb);
  }
  gemm(ATTb, ta_wo_t, ta_bo, R3, nullptr, DD, DD, 0);
  add_ln<<<MTOK, 64, 0, stream>>>(R4, R3, ta_lw, ta_lb, R0, X0b);   // x2: R0 + X0b

  // ---- Stage C: FFN ----
  gemm(X0b, f_w1_t, f_b1, nullptr, HIDb, FFD, DD, 1);               // GELU, bf16 hidden
  gemm(HIDb, f_w2_t, f_b2, R3, nullptr, DD, FFD, 0);
  add_ln<<<MTOK, 64, 0, stream>>>(R0, R3, f_lw, f_lb, out, nullptr);
}